// Round 2
// baseline (1215.073 us; speedup 1.0000x reference)
//
#include <hip/hip_runtime.h>
#include <hip/hip_bf16.h>
#include <math.h>

// Problem constants
#define BB 2
#define SS 2048
#define DD 2048
#define HH 32
#define HDD 64
#define MBB 16
#define NN 128

typedef unsigned short u16;
typedef short bf16x8_t __attribute__((ext_vector_type(8)));
typedef short bf16x4_t __attribute__((ext_vector_type(4)));
typedef float f32x4_t __attribute__((ext_vector_type(4)));

__device__ __forceinline__ float b2f(u16 u) { return __uint_as_float(((unsigned)u) << 16); }
__device__ __forceinline__ u16 f2b(float f) {
    unsigned u = __float_as_uint(f);
    return (u16)((u + 0x7FFFu + ((u >> 16) & 1u)) >> 16);
}
__device__ __forceinline__ unsigned pk2(float a, float b) {
    return (unsigned)f2b(a) | ((unsigned)f2b(b) << 16);
}
__device__ __forceinline__ unsigned pk2r(u16 a, u16 b) { return (unsigned)a | ((unsigned)b << 16); }
__device__ __forceinline__ float wsum(float x) {
    x += __shfl_xor(x, 32);
    x += __shfl_xor(x, 16);
    x += __shfl_xor(x, 8);
    x += __shfl_xor(x, 4);
    x += __shfl_xor(x, 2);
    x += __shfl_xor(x, 1);
    return x;
}

typedef __attribute__((address_space(3))) unsigned int lds_u32;
typedef __attribute__((address_space(1))) const unsigned int glb_u32;
__device__ __forceinline__ void async_copy16(const void* g, void* l) {
    __builtin_amdgcn_global_load_lds((glb_u32*)g, (lds_u32*)l, 16, 0, 0);
}

// ---------------- fused fp32 -> bf16 for x + 4 weight matrices ----------------
// grid (4096, 6): slice 0,1 = x halves; 2..5 = Wq,Wk,Wv,Wo. 4194304 elems/slice.
__global__ __launch_bounds__(256) void k_cvt5(const float* __restrict__ x, const float* __restrict__ wq,
                                              const float* __restrict__ wk, const float* __restrict__ wv,
                                              const float* __restrict__ wo, u16* __restrict__ xb,
                                              u16* __restrict__ wqb, u16* __restrict__ wkb,
                                              u16* __restrict__ wvb, u16* __restrict__ wob) {
    int sl = blockIdx.y;
    long e = (long)(blockIdx.x * 256 + threadIdx.x) * 4;
    const float* s;
    u16* d;
    if (sl == 0) { s = x; d = xb; }
    else if (sl == 1) { s = x + 4194304; d = xb + 4194304; }
    else if (sl == 2) { s = wq; d = wqb; }
    else if (sl == 3) { s = wk; d = wkb; }
    else if (sl == 4) { s = wv; d = wvb; }
    else { s = wo; d = wob; }
    float4 f = *(const float4*)(s + e);
    uint2 o;
    o.x = pk2(f.x, f.y);
    o.y = pk2(f.z, f.w);
    *(uint2*)(d + e) = o;
}

// ---------------- cos/sin tables ----------------
__global__ void k_trig(const float* __restrict__ pf, float* __restrict__ ct, float* __restrict__ st) {
    int i = blockIdx.x * 256 + threadIdx.x;  // 65536 = S*32
    float f = pf[i];
    ct[i] = cosf(f);
    st[i] = sinf(f);
}

// ---------------- bf16 MFMA GEMM:  C[M,N] = A[M,K] * B[N,K]^T ----------------
// blockIdx.z selects among up to 3 (B, C) pairs (fused QKV); pass same ptr and gridDim.z=1 otherwise.
// EPI 0: store fp32 row-major to Cout (M x N)
// EPI 1: apply RoPE, store bf16 to (B,H,S,HD) layout (qkv projections)
template <int EPI>
__global__ __launch_bounds__(256) void k_gemm_bt(const u16* __restrict__ A, const u16* __restrict__ B0,
                                                 const u16* __restrict__ B1, const u16* __restrict__ B2,
                                                 void* __restrict__ C0, void* __restrict__ C1,
                                                 void* __restrict__ C2, int M, int Nn, int K,
                                                 const float* __restrict__ ct, const float* __restrict__ st) {
    __shared__ u16 As[128 * 32];
    __shared__ u16 Bs[128 * 32];
    int z = blockIdx.z;
    const u16* Bm = (z == 0) ? B0 : (z == 1) ? B1 : B2;
    void* Cout = (z == 0) ? C0 : (z == 1) ? C1 : C2;
    int tid = threadIdx.x, lane = tid & 63, wv = tid >> 6;
    int m0 = blockIdx.y * 128, n0 = blockIdx.x * 128;
    int wm = wv >> 1, wn = wv & 1;

    f32x4_t acc[4][4];
    f32x4_t zero = {0.f, 0.f, 0.f, 0.f};
#pragma unroll
    for (int a = 0; a < 4; ++a)
#pragma unroll
        for (int b = 0; b < 4; ++b) acc[a][b] = zero;

    int mrow = lane & 15, qk = (lane >> 4) * 8;
    const int kTiles = K >> 5;
    for (int kt = 0; kt < kTiles; ++kt) {
        __syncthreads();
        int kb = kt << 5;
#pragma unroll
        for (int it = 0; it < 2; ++it) {
            int cb = it * 256 + wv * 64;  // wave-uniform chunk base
            int c = cb + lane;
            const u16* gpA = A + (m0 + (c >> 2)) * K + kb + ((c & 3) << 3);
            async_copy16(gpA, &As[cb << 3]);
            const u16* gpB = Bm + (n0 + (c >> 2)) * K + kb + ((c & 3) << 3);
            async_copy16(gpB, &Bs[cb << 3]);
        }
        asm volatile("s_waitcnt vmcnt(0)" ::: "memory");
        __syncthreads();

        bf16x8_t af[4], bfr[4];
#pragma unroll
        for (int mi = 0; mi < 4; ++mi)
            af[mi] = *(const bf16x8_t*)&As[(wm * 64 + mi * 16 + mrow) * 32 + qk];
#pragma unroll
        for (int ni = 0; ni < 4; ++ni)
            bfr[ni] = *(const bf16x8_t*)&Bs[(wn * 64 + ni * 16 + mrow) * 32 + qk];
#pragma unroll
        for (int mi = 0; mi < 4; ++mi)
#pragma unroll
            for (int ni = 0; ni < 4; ++ni)
                acc[mi][ni] = __builtin_amdgcn_mfma_f32_16x16x32_bf16(af[mi], bfr[ni], acc[mi][ni], 0, 0, 0);
    }

    int col16 = lane & 15, rq = (lane >> 4) * 4;
#pragma unroll
    for (int mi = 0; mi < 4; ++mi) {
#pragma unroll
        for (int ni = 0; ni < 4; ++ni) {
#pragma unroll
            for (int r = 0; r < 4; ++r) {
                int gr = m0 + wm * 64 + mi * 16 + rq + r;
                int gc = n0 + wn * 64 + ni * 16 + col16;
                float val = acc[mi][ni][r];
                if (EPI == 0) {
                    ((float*)Cout)[gr * Nn + gc] = val;
                } else {
                    // fused RoPE: pair partner sits on lane^1 (gc differs in bit 0)
                    int b = gr >> 11, s2 = gr & 2047, hh = gc >> 6, hd = gc & 63;
                    int fi = s2 * 32 + (hd >> 1);
                    float c = ct[fi], sn = st[fi];
                    float partner = __shfl_xor(val, 1);
                    float y = (gc & 1) ? (partner * sn + val * c) : (val * c - partner * sn);
                    ((u16*)Cout)[(((b * HH + hh) * SS) + s2) * HDD + hd] = f2b(y);
                }
            }
        }
    }
}

// ---------------- ilr gate: lr[b,h,s] = sigmoid(x[b,s,:].ilr_W[h] + ilr_b[h]) / HD ----------------
// 4 rows per block (ilr_W L2 reuse x4), bf16 x input.
__global__ __launch_bounds__(256) void k_lr(const u16* __restrict__ xb, const float* __restrict__ ilrW,
                                            const float* __restrict__ ilrb, float* __restrict__ lrout) {
    __shared__ u16 xr[4][2048];
    int row0 = blockIdx.x * 4;
    int tid = threadIdx.x, lane = tid & 63, wv = tid >> 6;
    const unsigned* src = (const unsigned*)(xb + row0 * 2048);
    unsigned* dst = (unsigned*)xr;
    for (int i = tid; i < 4096; i += 256) dst[i] = src[i];
    __syncthreads();
    int b = row0 >> 11, s0 = row0 & 2047;
#pragma unroll
    for (int sub = 0; sub < 8; ++sub) {
        int h = wv * 8 + sub;
        const float* wp = ilrW + h * 2048;
        float a0 = 0.f, a1 = 0.f, a2 = 0.f, a3 = 0.f;
        for (int i = 0; i < 16; ++i) {
            int idx = i * 128 + lane * 2;
            float2 w2 = *(const float2*)(wp + idx);
            unsigned p0 = *(const unsigned*)&xr[0][idx];
            unsigned p1 = *(const unsigned*)&xr[1][idx];
            unsigned p2 = *(const unsigned*)&xr[2][idx];
            unsigned p3 = *(const unsigned*)&xr[3][idx];
            a0 += b2f((u16)p0) * w2.x + b2f((u16)(p0 >> 16)) * w2.y;
            a1 += b2f((u16)p1) * w2.x + b2f((u16)(p1 >> 16)) * w2.y;
            a2 += b2f((u16)p2) * w2.x + b2f((u16)(p2 >> 16)) * w2.y;
            a3 += b2f((u16)p3) * w2.x + b2f((u16)(p3 >> 16)) * w2.y;
        }
        a0 = wsum(a0);
        a1 = wsum(a1);
        a2 = wsum(a2);
        a3 = wsum(a3);
        if (lane == 0) {
            float bv = ilrb[h];
            float* op = lrout + ((b * HH + h) * SS) + s0;
            op[0] = (1.0f / (1.0f + expf(-(a0 + bv)))) * (1.0f / 64.0f);
            op[1] = (1.0f / (1.0f + expf(-(a1 + bv)))) * (1.0f / 64.0f);
            op[2] = (1.0f / (1.0f + expf(-(a2 + bv)))) * (1.0f / 64.0f);
            op[3] = (1.0f / (1.0f + expf(-(a3 + bv)))) * (1.0f / 64.0f);
        }
    }
}

// ---------------- TTT scan: 8 WAVES per block, each wave = one independent (b,h) scan ----------------
// Rationale: the scan is latency-bound (85% stall with 1 wave/SIMD). Packing 8 independent
// scans into one block puts 2 waves on each SIMD so their stalls overlap. No barriers needed:
// each wave owns a private LDS slice.
// Layouts (16x16x32 bf16 MFMA, m89-verified):
//   A/B-frag: [row = lane&15][k = quad*8 + j]   (bf16x8)
//   C/D:      [row = quad*4 + reg][col = lane&15] (f32x4)
// Per-wave LDS strides: WbL 72 u16/row (b128 reads 16B-aligned, 2-way bank alias = free);
// XKT/GST 36 u16/row (frags read as 2x b64, 8B-aligned; 16 distinct banks per quad-group);
// PUL 40 u16/row. Per-wave total 19712 B, block total 157696 B <= 160 KiB.
__global__ __launch_bounds__(512) void k_scan(const u16* __restrict__ qb, const u16* __restrict__ kb2,
                                              const u16* __restrict__ vb, const float* __restrict__ lrbuf,
                                              const float* __restrict__ lgs, const float* __restrict__ tg,
                                              const float* __restrict__ tb, const float* __restrict__ W0,
                                              const float* __restrict__ b0, u16* __restrict__ ys) {
    __shared__ u16 WbL[8][64 * 72];  // [d2][d1]
    __shared__ u16 XKT[8][64 * 36];  // [d1][j(32)]  j>=16 stays 0
    __shared__ u16 GST[8][64 * 36];  // [d2][j(32)]  j>=16 stays 0
    __shared__ u16 PUL[8][16 * 40];  // [i][j(32)]   j>=16 stays 0 (bf16)

    const int w = threadIdx.x >> 6;
    const int bh = blockIdx.x * 8 + w, h = bh & 31, b = bh >> 5;
    const int lane = threadIdx.x & 63;
    const int quad = lane >> 4, col = lane & 15;
    const int base = bh * SS;

    u16* const WbLw = WbL[w];
    u16* const XKTw = XKT[w];
    u16* const GSTw = GST[w];
    u16* const PULw = PUL[w];

    {  // zero-init (upper j-halves must stay zero forever)
        unsigned* p1 = (unsigned*)XKTw;
        unsigned* p2 = (unsigned*)GSTw;
        unsigned* p3 = (unsigned*)PULw;
        for (int i = lane; i < 1152; i += 64) { p1[i] = 0; p2[i] = 0; }
        for (int i = lane; i < 320; i += 64) p3[i] = 0;
    }

    float gd4[4], bd4[4], bbv[4];
#pragma unroll
    for (int tn = 0; tn < 4; ++tn) {
        gd4[tn] = tg[h * 64 + tn * 16 + col];
        bd4[tn] = tb[h * 64 + tn * 16 + col];
        bbv[tn] = b0[h * 64 + tn * 16 + col];
    }
    float gs4[4];
#pragma unroll
    for (int r = 0; r < 4; ++r) {
        int i = quad * 4 + r;
        gs4[r] = fmaxf(1.f / (float)(i + 1) + lgs[i], 0.f);
    }
    const float gs15 = fmaxf(1.f / 16.f + lgs[15], 0.f);

    f32x4_t Wc[4][4];
#pragma unroll
    for (int tm = 0; tm < 4; ++tm)
#pragma unroll
        for (int tn = 0; tn < 4; ++tn)
#pragma unroll
            for (int r = 0; r < 4; ++r)
                Wc[tm][tn][r] = W0[h * 4096 + (tm * 16 + quad * 4 + r) * 64 + tn * 16 + col];

    {  // initial Wb
        unsigned* wb32 = (unsigned*)WbLw;
#pragma unroll
        for (int tn = 0; tn < 4; ++tn)
#pragma unroll
            for (int tm = 0; tm < 4; ++tm) {
                // row stride 36 u32; d1 word offset = tm*8 + quad*2
                int a = (tn * 16 + col) * 36 + tm * 8 + quad * 2;
                wb32[a] = pk2(Wc[tm][tn][0], Wc[tm][tn][1]);
                wb32[a + 1] = pk2(Wc[tm][tn][2], Wc[tm][tn][3]);
            }
    }

    // prefetch chunk 0: A-frags of XK/XQ, lr, and C-layout kraw/vraw
    bf16x8_t ka[2], qa[2];
    float lr4[4];
    u16 kraw[16], vraw[16];
    {
        const u16* kp = kb2 + (base + col) * 64;
        const u16* qp = qb + (base + col) * 64;
#pragma unroll
        for (int kh = 0; kh < 2; ++kh) {
            ka[kh] = *(const bf16x8_t*)(kp + kh * 32 + quad * 8);
            qa[kh] = *(const bf16x8_t*)(qp + kh * 32 + quad * 8);
        }
#pragma unroll
        for (int r = 0; r < 4; ++r) lr4[r] = lrbuf[base + quad * 4 + r];
#pragma unroll
        for (int tn = 0; tn < 4; ++tn)
#pragma unroll
            for (int r = 0; r < 4; ++r) {
                int idx = (base + quad * 4 + r) * 64 + tn * 16 + col;
                kraw[tn * 4 + r] = kb2[idx];
                vraw[tn * 4 + r] = vb[idx];
            }
    }

    const f32x4_t zf = {0.f, 0.f, 0.f, 0.f};

    for (int n = 0; n < NN; ++n) {
        const int s0 = n * 16;

        // W B-frags (written end of previous step)
        bf16x8_t wbf[4][2];
#pragma unroll
        for (int tn = 0; tn < 4; ++tn)
#pragma unroll
            for (int kh = 0; kh < 2; ++kh)
                wbf[tn][kh] = *(const bf16x8_t*)&WbLw[(tn * 16 + col) * 72 + kh * 32 + quad * 8];

        // Z = XK@W, XQW = XQ@W, Attn = XQ@XK^T  (vs old W)
        f32x4_t z[4], xqw[4], attn;
#pragma unroll
        for (int tn = 0; tn < 4; ++tn) {
            z[tn] = __builtin_amdgcn_mfma_f32_16x16x32_bf16(ka[1], wbf[tn][1], zf, 0, 0, 0);
            z[tn] = __builtin_amdgcn_mfma_f32_16x16x32_bf16(ka[0], wbf[tn][0], z[tn], 0, 0, 0);
            xqw[tn] = __builtin_amdgcn_mfma_f32_16x16x32_bf16(qa[1], wbf[tn][1], zf, 0, 0, 0);
            xqw[tn] = __builtin_amdgcn_mfma_f32_16x16x32_bf16(qa[0], wbf[tn][0], xqw[tn], 0, 0, 0);
        }
        attn = __builtin_amdgcn_mfma_f32_16x16x32_bf16(qa[1], ka[1], zf, 0, 0, 0);
        attn = __builtin_amdgcn_mfma_f32_16x16x32_bf16(qa[0], ka[0], attn, 0, 0, 0);

        // qraw (current step, used only in epilogue — issue now, latency covered)
        u16 qraw[16];
#pragma unroll
        for (int tn = 0; tn < 4; ++tn)
#pragma unroll
            for (int r = 0; r < 4; ++r)
                qraw[tn * 4 + r] = qb[(base + s0 + quad * 4 + r) * 64 + tn * 16 + col];

        // prefetch next chunk: A-frags, lr, kraw/vraw (clamped on last iter)
        bf16x8_t nka[2], nqa[2];
        float nlr[4];
        u16 nkraw[16], nvraw[16];
        {
            const int sp = (n + 1 < NN) ? s0 + 16 : s0;
            const u16* kp = kb2 + (base + sp + col) * 64;
            const u16* qp = qb + (base + sp + col) * 64;
#pragma unroll
            for (int kh = 0; kh < 2; ++kh) {
                nka[kh] = *(const bf16x8_t*)(kp + kh * 32 + quad * 8);
                nqa[kh] = *(const bf16x8_t*)(qp + kh * 32 + quad * 8);
            }
#pragma unroll
            for (int r = 0; r < 4; ++r) nlr[r] = lrbuf[base + sp + quad * 4 + r];
#pragma unroll
            for (int tn = 0; tn < 4; ++tn)
#pragma unroll
                for (int r = 0; r < 4; ++r) {
                    int idx = (base + sp + quad * 4 + r) * 64 + tn * 16 + col;
                    nkraw[tn * 4 + r] = kb2[idx];
                    nvraw[tn * 4 + r] = vb[idx];
                }
        }

        // XK^T into LDS (from regs prefetched last step)
        {
            unsigned* x32 = (unsigned*)XKTw;
#pragma unroll
            for (int tn = 0; tn < 4; ++tn) {
                int a = (tn * 16 + col) * 18 + quad * 2;  // u32 units; row stride 18 u32
                x32[a] = pk2r(kraw[tn * 4 + 0], kraw[tn * 4 + 1]);
                x32[a + 1] = pk2r(kraw[tn * 4 + 2], kraw[tn * 4 + 3]);
            }
        }

        // Z += bb ; grad = ln_l2_bwd(Z, XV-XK)
#pragma unroll
        for (int tn = 0; tn < 4; ++tn)
#pragma unroll
            for (int r = 0; r < 4; ++r) z[tn][r] += bbv[tn];

        float mu4[4], rstd4[4], m1[4], m2[4];
#pragma unroll
        for (int r = 0; r < 4; ++r) {
            float s1 = z[0][r] + z[1][r] + z[2][r] + z[3][r];
            float s2 = z[0][r] * z[0][r] + z[1][r] * z[1][r] + z[2][r] * z[2][r] + z[3][r] * z[3][r];
#pragma unroll
            for (int m = 1; m <= 8; m <<= 1) { s1 += __shfl_xor(s1, m); s2 += __shfl_xor(s2, m); }
            float mu = s1 * (1.f / 64.f);
            float var = s2 * (1.f / 64.f) - mu * mu;
            mu4[r] = mu;
            rstd4[r] = rsqrtf(var + 1e-5f);
            m1[r] = 0.f;
            m2[r] = 0.f;
        }
#pragma unroll
        for (int tn = 0; tn < 4; ++tn)
#pragma unroll
            for (int r = 0; r < 4; ++r) {
                float zh = (z[tn][r] - mu4[r]) * rstd4[r];
                float tgt = b2f(vraw[tn * 4 + r]) - b2f(kraw[tn * 4 + r]);
                float dzh = (gd4[tn] * zh + bd4[tn] - tgt) * gd4[tn];
                m1[r] += dzh;
                m2[r] += dzh * zh;
            }
#pragma unroll
        for (int r = 0; r < 4; ++r) {
#pragma unroll
            for (int m = 1; m <= 8; m <<= 1) { m1[r] += __shfl_xor(m1[r], m); m2[r] += __shfl_xor(m2[r], m); }
            m1[r] *= (1.f / 64.f);
            m2[r] *= (1.f / 64.f);
        }
        float gS[4][4];  // lr[j] * grad[j][d]  (C-layout)
#pragma unroll
        for (int tn = 0; tn < 4; ++tn)
#pragma unroll
            for (int r = 0; r < 4; ++r) {
                float zh = (z[tn][r] - mu4[r]) * rstd4[r];
                float tgt = b2f(vraw[tn * 4 + r]) - b2f(kraw[tn * 4 + r]);
                float dzh = (gd4[tn] * zh + bd4[tn] - tgt) * gd4[tn];
                gS[tn][r] = lr4[r] * ((dzh - m1[r] - zh * m2[r]) * rstd4[r]);
            }
        {  // gradS^T into LDS
            unsigned* g32 = (unsigned*)GSTw;
#pragma unroll
            for (int tn = 0; tn < 4; ++tn) {
                int a = (tn * 16 + col) * 18 + quad * 2;
                g32[a] = pk2(gS[tn][0], gS[tn][1]);
                g32[a + 1] = pk2(gS[tn][2], gS[tn][3]);
            }
        }
        // Pu = tril(1 + Attn), stored as bf16 rows
#pragma unroll
        for (int r = 0; r < 4; ++r) {
            float pv = (col <= quad * 4 + r) ? (1.f + attn[r]) : 0.f;
            PULw[(quad * 4 + r) * 40 + col] = f2b(pv);
        }

        // fragment reads (XKT/GST stride 36 u16: two 8B-aligned b64 halves per frag)
        bf16x8_t xkf[4], gsf[4], puf;
#pragma unroll
        for (int t = 0; t < 4; ++t) {
            bf16x4_t xl = *(const bf16x4_t*)&XKTw[(t * 16 + col) * 36 + quad * 8];
            bf16x4_t xh = *(const bf16x4_t*)&XKTw[(t * 16 + col) * 36 + quad * 8 + 4];
            xkf[t] = __builtin_shufflevector(xl, xh, 0, 1, 2, 3, 4, 5, 6, 7);
            bf16x4_t gl = *(const bf16x4_t*)&GSTw[(t * 16 + col) * 36 + quad * 8];
            bf16x4_t gh = *(const bf16x4_t*)&GSTw[(t * 16 + col) * 36 + quad * 8 + 4];
            gsf[t] = __builtin_shufflevector(gl, gh, 0, 1, 2, 3, 4, 5, 6, 7);
        }
        puf = *(const bf16x8_t*)&PULw[col * 40 + quad * 8];

        // W update first (so next step's wbf read has the whole epilogue to cover latency)
#pragma unroll
        for (int tm = 0; tm < 4; ++tm)
#pragma unroll
            for (int tn = 0; tn < 4; ++tn) {
                f32x4_t dw = __builtin_amdgcn_mfma_f32_16x16x32_bf16(xkf[tm], gsf[tn], zf, 0, 0, 0);
#pragma unroll
                for (int r = 0; r < 4; ++r) Wc[tm][tn][r] -= gs15 * dw[r];
            }
        {
            unsigned* wb32 = (unsigned*)WbLw;
#pragma unroll
            for (int tn = 0; tn < 4; ++tn)
#pragma unroll
                for (int tm = 0; tm < 4; ++tm) {
                    int a = (tn * 16 + col) * 36 + tm * 8 + quad * 2;
                    wb32[a] = pk2(Wc[tm][tn][0], Wc[tm][tn][1]);
                    wb32[a + 1] = pk2(Wc[tm][tn][2], Wc[tm][tn][3]);
                }
        }

        // Z_bar = XQW + bb - gs[i] * (Pu @ gradS)   (reuse z as zbar)
#pragma unroll
        for (int tn = 0; tn < 4; ++tn) {
            f32x4_t pg = __builtin_amdgcn_mfma_f32_16x16x32_bf16(puf, gsf[tn], zf, 0, 0, 0);
#pragma unroll
            for (int r = 0; r < 4; ++r) z[tn][r] = xqw[tn][r] + bbv[tn] - gs4[r] * pg[r];
        }
        // y = XQ + ln_fwd(Z_bar)  -> bf16
#pragma unroll
        for (int r = 0; r < 4; ++r) {
            float s1 = z[0][r] + z[1][r] + z[2][r] + z[3][r];
            float s2 = z[0][r] * z[0][r] + z[1][r] * z[1][r] + z[2][r] * z[2][r] + z[3][r] * z[3][r];
#pragma unroll
            for (int m = 1; m <= 8; m <<= 1) { s1 += __shfl_xor(s1, m); s2 += __shfl_xor(s2, m); }
            float mu = s1 * (1.f / 64.f);
            float var = s2 * (1.f / 64.f) - mu * mu;
            mu4[r] = mu;
            rstd4[r] = rsqrtf(var + 1e-5f);
        }
#pragma unroll
        for (int tn = 0; tn < 4; ++tn)
#pragma unroll
            for (int r = 0; r < 4; ++r) {
                float y = b2f(qraw[tn * 4 + r]) + gd4[tn] * (z[tn][r] - mu4[r]) * rstd4[r] + bd4[tn];
                ys[(b * SS + s0 + quad * 4 + r) * DD + h * 64 + tn * 16 + col] = f2b(y);
            }

        // b update: bb -= gs15 * colsum(gradS)
#pragma unroll
        for (int tn = 0; tn < 4; ++tn) {
            float c = gS[tn][0] + gS[tn][1] + gS[tn][2] + gS[tn][3];
            c += __shfl_xor(c, 16);
            c += __shfl_xor(c, 32);
            bbv[tn] -= gs15 * c;
        }

        ka[0] = nka[0]; ka[1] = nka[1];
        qa[0] = nqa[0]; qa[1] = nqa[1];
#pragma unroll
        for (int r = 0; r < 4; ++r) lr4[r] = nlr[r];
#pragma unroll
        for (int j = 0; j < 16; ++j) { kraw[j] = nkraw[j]; vraw[j] = nvraw[j]; }
    }
}

// ---------------- post layernorm (bf16 in) -> bf16 out ----------------
__global__ __launch_bounds__(256) void k_postln(const u16* __restrict__ ys, const float* __restrict__ pg,
                                                const float* __restrict__ pb, u16* __restrict__ outb) {
    __shared__ float red[8];
    int row = blockIdx.x, tid = threadIdx.x, lane = tid & 63, wv = tid >> 6;
    const u16* rp = ys + row * 2048 + tid * 8;
    uint4 pkd = *(const uint4*)rp;
    float v[8];
    v[0] = b2f((u16)pkd.x); v[1] = b2f((u16)(pkd.x >> 16));
    v[2] = b2f((u16)pkd.y); v[3] = b2f((u16)(pkd.y >> 16));
    v[4] = b2f((u16)pkd.z); v[5] = b2f((u16)(pkd.z >> 16));
    v[6] = b2f((u16)pkd.w); v[7] = b2f((u16)(pkd.w >> 16));
    float s1 = 0.f, s2 = 0.f;
#pragma unroll
    for (int i = 0; i < 8; ++i) { s1 += v[i]; s2 += v[i] * v[i]; }
    s1 = wsum(s1);
    s2 = wsum(s2);
    if (lane == 0) {
        red[wv] = s1;
        red[wv + 4] = s2;
    }
    __syncthreads();
    float S1 = red[0] + red[1] + red[2] + red[3];
    float S2 = red[4] + red[5] + red[6] + red[7];
    float mu = S1 * (1.f / 2048), var = S2 * (1.f / 2048) - mu * mu;
    float rstd = rsqrtf(var + 1e-5f);
    const float4 g0 = *(const float4*)(pg + tid * 8);
    const float4 g1 = *(const float4*)(pg + tid * 8 + 4);
    const float4 b0v = *(const float4*)(pb + tid * 8);
    const float4 b1v = *(const float4*)(pb + tid * 8 + 4);
    float o[8];
    o[0] = g0.x * (v[0] - mu) * rstd + b0v.x;
    o[1] = g0.y * (v[1] - mu) * rstd + b0v.y;
    o[2] = g0.z * (v[2] - mu) * rstd + b0v.z;
    o[3] = g0.w * (v[3] - mu) * rstd + b0v.w;
    o[4] = g1.x * (v[4] - mu) * rstd + b1v.x;
    o[5] = g1.y * (v[5] - mu) * rstd + b1v.y;
    o[6] = g1.z * (v[6] - mu) * rstd + b1v.z;
    o[7] = g1.w * (v[7] - mu) * rstd + b1v.w;
    uint4 po;
    po.x = pk2(o[0], o[1]);
    po.y = pk2(o[2], o[3]);
    po.z = pk2(o[4], o[5]);
    po.w = pk2(o[6], o[7]);
    *(uint4*)(outb + row * 2048 + tid * 8) = po;
}

extern "C" void kernel_launch(void* const* d_in, const int* in_sizes, int n_in,
                              void* d_out, int out_size, void* d_ws, size_t ws_size,
                              hipStream_t stream) {
    const float* x = (const float*)d_in[0];
    const float* pf = (const float*)d_in[1];
    const float* Wq = (const float*)d_in[2];
    const float* Wk = (const float*)d_in[3];
    const float* Wv = (const float*)d_in[4];
    const float* Wo = (const float*)d_in[5];
    const float* pg = (const float*)d_in[6];
    const float* pb = (const float*)d_in[7];
    const float* ilrW = (const float*)d_in[8];
    const float* ilrb = (const float*)d_in[9];
    const float* lgs = (const float*)d_in[10];
    const float* tg = (const float*)d_in[11];
    const float* tb = (const float*)d_in[12];
    const float* W0 = (const float*)d_in[13];
    const float* b0 = (const float*)d_in[14];
    float* out = (float*)d_out;
    char* ws = (char*)d_ws;

    // workspace layout
    u16* xbf = (u16*)(ws + 0);             // 16 MB  (reused as lnb later)
    u16* wqb = (u16*)(ws + 16777216);      // 8 MB
    u16* wkb = (u16*)(ws + 25165824);      // 8 MB
    u16* wvb = (u16*)(ws + 33554432);      // 8 MB
    u16* wob = (u16*)(ws + 41943040);      // 8 MB
    u16* qbuf = (u16*)(ws + 50331648);     // 16 MB
    u16* kbuf = (u16*)(ws + 67108864);     // 16 MB
    u16* vbuf = (u16*)(ws + 83886080);     // 16 MB
    float* ct = (float*)(ws + 100663296);  // 256 KB
    float* st = (float*)(ws + 100925440);  // 256 KB
    float* lrb = (float*)(ws + 101187584); // 512 KB
    u16* ysb = (u16*)(ws + 101711872);     // 16 MB (bf16 now)
    u16* lnb = (u16*)(ws + 0);             // reuse xbf region (dead after QKV GEMMs)

    k_cvt5<<<dim3(4096, 6), 256, 0, stream>>>(x, Wq, Wk, Wv, Wo, xbf, wqb, wkb, wvb, wob);
    k_trig<<<256, 256, 0, stream>>>(pf, ct, st);

    k_gemm_bt<1><<<dim3(16, 32, 3), 256, 0, stream>>>(xbf, wqb, wkb, wvb, qbuf, kbuf, vbuf,
                                                      4096, 2048, 2048, ct, st);

    k_lr<<<1024, 256, 0, stream>>>(xbf, ilrW, ilrb, lrb);

    k_scan<<<dim3(8), 512, 0, stream>>>(qbuf, kbuf, vbuf, lrb, lgs, tg, tb, W0, b0, ysb);

    k_postln<<<4096, 256, 0, stream>>>(ysb, pg, pb, lnb);
    k_gemm_bt<0><<<dim3(16, 32, 1), 256, 0, stream>>>(lnb, wob, wob, wob, out, out, out,
                                                      4096, 2048, 2048, nullptr, nullptr);
}

// Round 3
// 876.273 us; speedup vs baseline: 1.3866x; 1.3866x over previous
//
#include <hip/hip_runtime.h>
#include <hip/hip_bf16.h>
#include <math.h>

// Problem constants
#define BB 2
#define SS 2048
#define DD 2048
#define HH 32
#define HDD 64
#define MBB 16
#define NN 128

typedef unsigned short u16;
typedef short bf16x8_t __attribute__((ext_vector_type(8)));
typedef float f32x4_t __attribute__((ext_vector_type(4)));

__device__ __forceinline__ float b2f(u16 u) { return __uint_as_float(((unsigned)u) << 16); }
__device__ __forceinline__ u16 f2b(float f) {
    unsigned u = __float_as_uint(f);
    return (u16)((u + 0x7FFFu + ((u >> 16) & 1u)) >> 16);
}
__device__ __forceinline__ unsigned pk2(float a, float b) {
    return (unsigned)f2b(a) | ((unsigned)f2b(b) << 16);
}
__device__ __forceinline__ unsigned pk2r(u16 a, u16 b) { return (unsigned)a | ((unsigned)b << 16); }
__device__ __forceinline__ float wsum(float x) {
    x += __shfl_xor(x, 32);
    x += __shfl_xor(x, 16);
    x += __shfl_xor(x, 8);
    x += __shfl_xor(x, 4);
    x += __shfl_xor(x, 2);
    x += __shfl_xor(x, 1);
    return x;
}

typedef __attribute__((address_space(3))) unsigned int lds_u32;
typedef __attribute__((address_space(1))) const unsigned int glb_u32;
__device__ __forceinline__ void async_copy16(const void* g, void* l) {
    __builtin_amdgcn_global_load_lds((glb_u32*)g, (lds_u32*)l, 16, 0, 0);
}

// within-head permutation: perm(d) = (d&15)*4 + (d>>4);  inverse: d = (j>>2) + (j&3)*16

// ---------------- fused fp32 -> bf16 for x + 4 weight matrices ----------------
// grid (4096, 6): slice 0,1 = x halves; 2..5 = Wq,Wk,Wv,Wo. 4194304 elems/slice.
// Wo (slice 5) is stored with permuted k-columns (wob[n, j] = Wo[n, (j>>2)+(j&3)*16] per head)
// to match the permuted lnb produced by k_scan/k_postln; C = A@B^T invariant under joint k-perm.
__global__ __launch_bounds__(256) void k_cvt5(const float* __restrict__ x, const float* __restrict__ wq,
                                              const float* __restrict__ wk, const float* __restrict__ wv,
                                              const float* __restrict__ wo, u16* __restrict__ xb,
                                              u16* __restrict__ wqb, u16* __restrict__ wkb,
                                              u16* __restrict__ wvb, u16* __restrict__ wob) {
    int sl = blockIdx.y;
    long e = (long)(blockIdx.x * 256 + threadIdx.x) * 4;
    if (sl == 5) {
        // permuted Wo convert: 4 consecutive outputs j=e..e+3 share (j>>2); sources stride 16
        long n = e >> 11;
        int cin = (int)(e & 2047);
        int hd0 = (cin >> 6) * 64 + ((cin & 63) >> 2);
        const float* src = wo + n * 2048 + hd0;
        float f0 = src[0], f1 = src[16], f2 = src[32], f3 = src[48];
        uint2 o;
        o.x = pk2(f0, f1);
        o.y = pk2(f2, f3);
        *(uint2*)(wob + e) = o;
        return;
    }
    const float* s;
    u16* d;
    if (sl == 0) { s = x; d = xb; }
    else if (sl == 1) { s = x + 4194304; d = xb + 4194304; }
    else if (sl == 2) { s = wq; d = wqb; }
    else if (sl == 3) { s = wk; d = wkb; }
    else { s = wv; d = wvb; }
    float4 f = *(const float4*)(s + e);
    uint2 o;
    o.x = pk2(f.x, f.y);
    o.y = pk2(f.z, f.w);
    *(uint2*)(d + e) = o;
}

// ---------------- cos/sin tables ----------------
__global__ void k_trig(const float* __restrict__ pf, float* __restrict__ ct, float* __restrict__ st) {
    int i = blockIdx.x * 256 + threadIdx.x;  // 65536 = S*32
    float f = pf[i];
    ct[i] = cosf(f);
    st[i] = sinf(f);
}

// ---------------- permuted post-LN gamma/beta ----------------
__global__ void k_ppg(const float* __restrict__ pg, const float* __restrict__ pb,
                      float* __restrict__ pgp, float* __restrict__ pbp) {
    int i = blockIdx.x * 256 + threadIdx.x;  // 2048
    int h = i >> 6, o = i & 63;
    int src = h * 64 + (o >> 2) + (o & 3) * 16;
    pgp[i] = pg[src];
    pbp[i] = pb[src];
}

// ---------------- build permuted copies of q,k for the scan's C-layout gathers ----------------
// qc/kc[(row)*64 + (d&15)*4 + (d>>4)] = qbuf/kbuf[(row)*64 + d];  one row (64 u16) per thread.
__global__ __launch_bounds__(256) void k_prep(const u16* __restrict__ qb, const u16* __restrict__ kb,
                                              u16* __restrict__ qc, u16* __restrict__ kc) {
    long row = (long)blockIdx.x * 256 + threadIdx.x;  // 131072 rows per array
    const u16* src = (blockIdx.y == 0 ? qb : kb) + row * 64;
    u16* dst = (blockIdx.y == 0 ? qc : kc) + row * 64;
    u16 v[64];
#pragma unroll
    for (int i = 0; i < 8; ++i) *(uint4*)&v[i * 8] = *(const uint4*)(src + i * 8);
    u16 o[64];
#pragma unroll
    for (int d = 0; d < 64; ++d) o[(d & 15) * 4 + (d >> 4)] = v[d];
#pragma unroll
    for (int i = 0; i < 8; ++i) *(uint4*)(dst + i * 8) = *(uint4*)&o[i * 8];
}

// ---------------- bf16 MFMA GEMM:  C[M,N] = A[M,K] * B[N,K]^T ----------------
// blockIdx.z selects among up to 3 (B, C) pairs (fused QKV); pass same ptr and gridDim.z=1 otherwise.
// EPI 0: store fp32 row-major to Cout (M x N)
// EPI 1: apply RoPE, store bf16 to (B,H,S,HD) layout; z==2 (V) stores with within-head perm
template <int EPI>
__global__ __launch_bounds__(256) void k_gemm_bt(const u16* __restrict__ A, const u16* __restrict__ B0,
                                                 const u16* __restrict__ B1, const u16* __restrict__ B2,
                                                 void* __restrict__ C0, void* __restrict__ C1,
                                                 void* __restrict__ C2, int M, int Nn, int K,
                                                 const float* __restrict__ ct, const float* __restrict__ st) {
    __shared__ u16 As[128 * 32];
    __shared__ u16 Bs[128 * 32];
    int z = blockIdx.z;
    const u16* Bm = (z == 0) ? B0 : (z == 1) ? B1 : B2;
    void* Cout = (z == 0) ? C0 : (z == 1) ? C1 : C2;
    int tid = threadIdx.x, lane = tid & 63, wv = tid >> 6;
    int m0 = blockIdx.y * 128, n0 = blockIdx.x * 128;
    int wm = wv >> 1, wn = wv & 1;

    f32x4_t acc[4][4];
    f32x4_t zero = {0.f, 0.f, 0.f, 0.f};
#pragma unroll
    for (int a = 0; a < 4; ++a)
#pragma unroll
        for (int b = 0; b < 4; ++b) acc[a][b] = zero;

    int mrow = lane & 15, qk = (lane >> 4) * 8;
    const int kTiles = K >> 5;
    for (int kt = 0; kt < kTiles; ++kt) {
        __syncthreads();
        int kb = kt << 5;
#pragma unroll
        for (int it = 0; it < 2; ++it) {
            int cb = it * 256 + wv * 64;  // wave-uniform chunk base
            int c = cb + lane;
            const u16* gpA = A + (m0 + (c >> 2)) * K + kb + ((c & 3) << 3);
            async_copy16(gpA, &As[cb << 3]);
            const u16* gpB = Bm + (n0 + (c >> 2)) * K + kb + ((c & 3) << 3);
            async_copy16(gpB, &Bs[cb << 3]);
        }
        asm volatile("s_waitcnt vmcnt(0)" ::: "memory");
        __syncthreads();

        bf16x8_t af[4], bfr[4];
#pragma unroll
        for (int mi = 0; mi < 4; ++mi)
            af[mi] = *(const bf16x8_t*)&As[(wm * 64 + mi * 16 + mrow) * 32 + qk];
#pragma unroll
        for (int ni = 0; ni < 4; ++ni)
            bfr[ni] = *(const bf16x8_t*)&Bs[(wn * 64 + ni * 16 + mrow) * 32 + qk];
#pragma unroll
        for (int mi = 0; mi < 4; ++mi)
#pragma unroll
            for (int ni = 0; ni < 4; ++ni)
                acc[mi][ni] = __builtin_amdgcn_mfma_f32_16x16x32_bf16(af[mi], bfr[ni], acc[mi][ni], 0, 0, 0);
    }

    int col16 = lane & 15, rq = (lane >> 4) * 4;
#pragma unroll
    for (int mi = 0; mi < 4; ++mi) {
#pragma unroll
        for (int ni = 0; ni < 4; ++ni) {
#pragma unroll
            for (int r = 0; r < 4; ++r) {
                int gr = m0 + wm * 64 + mi * 16 + rq + r;
                int gc = n0 + wn * 64 + ni * 16 + col16;
                float val = acc[mi][ni][r];
                if (EPI == 0) {
                    ((float*)Cout)[gr * Nn + gc] = val;
                } else {
                    // fused RoPE: pair partner sits on lane^1 (gc differs in bit 0)
                    int b = gr >> 11, s2 = gr & 2047, hh = gc >> 6, hd = gc & 63;
                    int fi = s2 * 32 + (hd >> 1);
                    float c = ct[fi], sn = st[fi];
                    float partner = __shfl_xor(val, 1);
                    float y = (gc & 1) ? (partner * sn + val * c) : (val * c - partner * sn);
                    int po = (z == 2) ? ((hd & 15) * 4 + (hd >> 4)) : hd;  // V stored permuted
                    ((u16*)Cout)[(((b * HH + hh) * SS) + s2) * HDD + po] = f2b(y);
                }
            }
        }
    }
}

// ---------------- ilr gate: lr[b,h,s] = sigmoid(x[b,s,:].ilr_W[h] + ilr_b[h]) / HD ----------------
__global__ __launch_bounds__(256) void k_lr(const u16* __restrict__ xb, const float* __restrict__ ilrW,
                                            const float* __restrict__ ilrb, float* __restrict__ lrout) {
    __shared__ u16 xr[4][2048];
    int row0 = blockIdx.x * 4;
    int tid = threadIdx.x, lane = tid & 63, wv = tid >> 6;
    const unsigned* src = (const unsigned*)(xb + row0 * 2048);
    unsigned* dst = (unsigned*)xr;
    for (int i = tid; i < 4096; i += 256) dst[i] = src[i];
    __syncthreads();
    int b = row0 >> 11, s0 = row0 & 2047;
#pragma unroll
    for (int sub = 0; sub < 8; ++sub) {
        int h = wv * 8 + sub;
        const float* wp = ilrW + h * 2048;
        float a0 = 0.f, a1 = 0.f, a2 = 0.f, a3 = 0.f;
        for (int i = 0; i < 16; ++i) {
            int idx = i * 128 + lane * 2;
            float2 w2 = *(const float2*)(wp + idx);
            unsigned p0 = *(const unsigned*)&xr[0][idx];
            unsigned p1 = *(const unsigned*)&xr[1][idx];
            unsigned p2 = *(const unsigned*)&xr[2][idx];
            unsigned p3 = *(const unsigned*)&xr[3][idx];
            a0 += b2f((u16)p0) * w2.x + b2f((u16)(p0 >> 16)) * w2.y;
            a1 += b2f((u16)p1) * w2.x + b2f((u16)(p1 >> 16)) * w2.y;
            a2 += b2f((u16)p2) * w2.x + b2f((u16)(p2 >> 16)) * w2.y;
            a3 += b2f((u16)p3) * w2.x + b2f((u16)(p3 >> 16)) * w2.y;
        }
        a0 = wsum(a0);
        a1 = wsum(a1);
        a2 = wsum(a2);
        a3 = wsum(a3);
        if (lane == 0) {
            float bv = ilrb[h];
            float* op = lrout + ((b * HH + h) * SS) + s0;
            op[0] = (1.0f / (1.0f + expf(-(a0 + bv)))) * (1.0f / 64.0f);
            op[1] = (1.0f / (1.0f + expf(-(a1 + bv)))) * (1.0f / 64.0f);
            op[2] = (1.0f / (1.0f + expf(-(a2 + bv)))) * (1.0f / 64.0f);
            op[3] = (1.0f / (1.0f + expf(-(a3 + bv)))) * (1.0f / 64.0f);
        }
    }
}

// ---------------- TTT scan: ONE WAVE per (b,h) ----------------
// 64 blocks x 1 wave (spread over 64 CUs, ~1 wave/SIMD).  vs the 442us baseline:
//  * all C-layout global gathers (kraw/vraw/qraw) served by permuted copies -> ushort4 loads
//  * ys stored permuted -> ushort4 stores (postln works in perm space)
//  * XKT write + xkf read and wbf read hoisted to end-of-step (operands in regs at step start)
//  * launch_bounds(64,1): single wave may use up to 512 VGPR, no spill
__global__ __launch_bounds__(64, 1) void k_scan(const u16* __restrict__ qb, const u16* __restrict__ kb2,
                                                const u16* __restrict__ qc, const u16* __restrict__ kc,
                                                const u16* __restrict__ vc, const float* __restrict__ lrbuf,
                                                const float* __restrict__ lgs, const float* __restrict__ tg,
                                                const float* __restrict__ tb, const float* __restrict__ W0,
                                                const float* __restrict__ b0, u16* __restrict__ ys) {
    __shared__ u16 WbL[64 * 72];  // [d2][d1]
    __shared__ u16 XKT[64 * 40];  // [d1][j(32)]  j>=16 stays 0
    __shared__ u16 GST[64 * 40];  // [d2][j(32)]  j>=16 stays 0
    __shared__ u16 PUL[16 * 40];  // [i][j(32)]   j>=16 stays 0 (bf16)

    const int bh = blockIdx.x, h = bh & 31, b = bh >> 5;
    const int lane = threadIdx.x & 63;
    const int quad = lane >> 4, col = lane & 15;
    const int base = bh * SS;

    {  // zero-init (upper j-halves must stay zero forever)
        unsigned* p1 = (unsigned*)XKT;
        unsigned* p2 = (unsigned*)GST;
        unsigned* p3 = (unsigned*)PUL;
        for (int i = lane; i < 1280; i += 64) { p1[i] = 0; p2[i] = 0; }
        for (int i = lane; i < 320; i += 64) p3[i] = 0;
    }

    float gd4[4], bd4[4], bbv[4];
#pragma unroll
    for (int tn = 0; tn < 4; ++tn) {
        gd4[tn] = tg[h * 64 + tn * 16 + col];
        bd4[tn] = tb[h * 64 + tn * 16 + col];
        bbv[tn] = b0[h * 64 + tn * 16 + col];
    }
    float gs4[4];
#pragma unroll
    for (int r = 0; r < 4; ++r) {
        int i = quad * 4 + r;
        gs4[r] = fmaxf(1.f / (float)(i + 1) + lgs[i], 0.f);
    }
    const float gs15 = fmaxf(1.f / 16.f + lgs[15], 0.f);

    f32x4_t Wc[4][4];
#pragma unroll
    for (int tm = 0; tm < 4; ++tm)
#pragma unroll
        for (int tn = 0; tn < 4; ++tn)
#pragma unroll
            for (int r = 0; r < 4; ++r)
                Wc[tm][tn][r] = W0[h * 4096 + (tm * 16 + quad * 4 + r) * 64 + tn * 16 + col];

    {  // initial Wb
        unsigned* wb32 = (unsigned*)WbL;
#pragma unroll
        for (int tn = 0; tn < 4; ++tn)
#pragma unroll
            for (int tm = 0; tm < 4; ++tm) {
                int a = (tn * 16 + col) * 36 + tm * 8 + quad * 2;  // u32 units; row stride 36 u32
                wb32[a] = pk2(Wc[tm][tn][0], Wc[tm][tn][1]);
                wb32[a + 1] = pk2(Wc[tm][tn][2], Wc[tm][tn][3]);
            }
    }

    // prefetch chunk 0: A-frags of XK/XQ, lr, and perm-layout kraw/vraw/qraw
    bf16x8_t ka[2], qa[2];
    float lr4[4];
    u16 kraw[16], vraw[16], qraw[16];
    {
        const u16* kp = kb2 + (base + col) * 64;
        const u16* qp = qb + (base + col) * 64;
#pragma unroll
        for (int kh = 0; kh < 2; ++kh) {
            ka[kh] = *(const bf16x8_t*)(kp + kh * 32 + quad * 8);
            qa[kh] = *(const bf16x8_t*)(qp + kh * 32 + quad * 8);
        }
#pragma unroll
        for (int r = 0; r < 4; ++r) lr4[r] = lrbuf[base + quad * 4 + r];
#pragma unroll
        for (int r = 0; r < 4; ++r) {
            long ro = (long)(base + quad * 4 + r) * 64 + col * 4;
            ushort4 tk = *(const ushort4*)(kc + ro);
            ushort4 tv = *(const ushort4*)(vc + ro);
            ushort4 tq = *(const ushort4*)(qc + ro);
            kraw[r] = tk.x; kraw[4 + r] = tk.y; kraw[8 + r] = tk.z; kraw[12 + r] = tk.w;
            vraw[r] = tv.x; vraw[4 + r] = tv.y; vraw[8 + r] = tv.z; vraw[12 + r] = tv.w;
            qraw[r] = tq.x; qraw[4 + r] = tq.y; qraw[8 + r] = tq.z; qraw[12 + r] = tq.w;
        }
    }

    // prologue: XKT(0) write + xkf(0) read; wbf(0) read (in-order LDS within the wave)
    bf16x8_t xkf[4], wbf[4][2];
    {
        unsigned* x32 = (unsigned*)XKT;
#pragma unroll
        for (int tn = 0; tn < 4; ++tn) {
            int a = (tn * 16 + col) * 20 + quad * 2;
            x32[a] = pk2r(kraw[tn * 4 + 0], kraw[tn * 4 + 1]);
            x32[a + 1] = pk2r(kraw[tn * 4 + 2], kraw[tn * 4 + 3]);
        }
#pragma unroll
        for (int t = 0; t < 4; ++t)
            xkf[t] = *(const bf16x8_t*)&XKT[(t * 16 + col) * 40 + quad * 8];
#pragma unroll
        for (int tn = 0; tn < 4; ++tn)
#pragma unroll
            for (int kh = 0; kh < 2; ++kh)
                wbf[tn][kh] = *(const bf16x8_t*)&WbL[(tn * 16 + col) * 72 + kh * 32 + quad * 8];
    }

    const f32x4_t zf = {0.f, 0.f, 0.f, 0.f};

    for (int n = 0; n < NN; ++n) {
        const int s0 = n * 16;

        // Z = XK@W, XQW = XQ@W, Attn = XQ@XK^T  (operands all in regs)
        f32x4_t z[4], xqw[4], attn;
#pragma unroll
        for (int tn = 0; tn < 4; ++tn) {
            z[tn] = __builtin_amdgcn_mfma_f32_16x16x32_bf16(ka[1], wbf[tn][1], zf, 0, 0, 0);
            z[tn] = __builtin_amdgcn_mfma_f32_16x16x32_bf16(ka[0], wbf[tn][0], z[tn], 0, 0, 0);
            xqw[tn] = __builtin_amdgcn_mfma_f32_16x16x32_bf16(qa[1], wbf[tn][1], zf, 0, 0, 0);
            xqw[tn] = __builtin_amdgcn_mfma_f32_16x16x32_bf16(qa[0], wbf[tn][0], xqw[tn], 0, 0, 0);
        }
        attn = __builtin_amdgcn_mfma_f32_16x16x32_bf16(qa[1], ka[1], zf, 0, 0, 0);
        attn = __builtin_amdgcn_mfma_f32_16x16x32_bf16(qa[0], ka[0], attn, 0, 0, 0);

        // Pu = tril(1 + Attn) -> LDS early (read back later, latency covered)
#pragma unroll
        for (int r = 0; r < 4; ++r) {
            float pv = (col <= quad * 4 + r) ? (1.f + attn[r]) : 0.f;
            PUL[(quad * 4 + r) * 40 + col] = f2b(pv);
        }

        // prefetch next chunk (clamped on last iter)
        bf16x8_t nka[2], nqa[2];
        float nlr[4];
        u16 nkraw[16], nvraw[16], nqraw[16];
        {
            const int sp = (n + 1 < NN) ? s0 + 16 : s0;
            const u16* kp = kb2 + (base + sp + col) * 64;
            const u16* qp = qb + (base + sp + col) * 64;
#pragma unroll
            for (int kh = 0; kh < 2; ++kh) {
                nka[kh] = *(const bf16x8_t*)(kp + kh * 32 + quad * 8);
                nqa[kh] = *(const bf16x8_t*)(qp + kh * 32 + quad * 8);
            }
#pragma unroll
            for (int r = 0; r < 4; ++r) nlr[r] = lrbuf[base + sp + quad * 4 + r];
#pragma unroll
            for (int r = 0; r < 4; ++r) {
                long ro = (long)(base + sp + quad * 4 + r) * 64 + col * 4;
                ushort4 tk = *(const ushort4*)(kc + ro);
                ushort4 tv = *(const ushort4*)(vc + ro);
                ushort4 tq = *(const ushort4*)(qc + ro);
                nkraw[r] = tk.x; nkraw[4 + r] = tk.y; nkraw[8 + r] = tk.z; nkraw[12 + r] = tk.w;
                nvraw[r] = tv.x; nvraw[4 + r] = tv.y; nvraw[8 + r] = tv.z; nvraw[12 + r] = tv.w;
                nqraw[r] = tq.x; nqraw[4 + r] = tq.y; nqraw[8 + r] = tq.z; nqraw[12 + r] = tq.w;
            }
        }

        // Z += bb ; grad = ln_l2_bwd(Z, XV-XK)
#pragma unroll
        for (int tn = 0; tn < 4; ++tn)
#pragma unroll
            for (int r = 0; r < 4; ++r) z[tn][r] += bbv[tn];

        float mu4[4], rstd4[4], m1[4], m2[4];
#pragma unroll
        for (int r = 0; r < 4; ++r) {
            float s1 = z[0][r] + z[1][r] + z[2][r] + z[3][r];
            float s2 = z[0][r] * z[0][r] + z[1][r] * z[1][r] + z[2][r] * z[2][r] + z[3][r] * z[3][r];
#pragma unroll
            for (int m = 1; m <= 8; m <<= 1) { s1 += __shfl_xor(s1, m); s2 += __shfl_xor(s2, m); }
            float mu = s1 * (1.f / 64.f);
            float var = s2 * (1.f / 64.f) - mu * mu;
            mu4[r] = mu;
            rstd4[r] = rsqrtf(var + 1e-5f);
            m1[r] = 0.f;
            m2[r] = 0.f;
        }
#pragma unroll
        for (int tn = 0; tn < 4; ++tn)
#pragma unroll
            for (int r = 0; r < 4; ++r) {
                float zh = (z[tn][r] - mu4[r]) * rstd4[r];
                float tgt = b2f(vraw[tn * 4 + r]) - b2f(kraw[tn * 4 + r]);
                float dzh = (gd4[tn] * zh + bd4[tn] - tgt) * gd4[tn];
                m1[r] += dzh;
                m2[r] += dzh * zh;
            }
#pragma unroll
        for (int r = 0; r < 4; ++r) {
#pragma unroll
            for (int m = 1; m <= 8; m <<= 1) { m1[r] += __shfl_xor(m1[r], m); m2[r] += __shfl_xor(m2[r], m); }
            m1[r] *= (1.f / 64.f);
            m2[r] *= (1.f / 64.f);
        }
        float gS[4][4];  // lr[j] * grad[j][d]  (C-layout)
#pragma unroll
        for (int tn = 0; tn < 4; ++tn)
#pragma unroll
            for (int r = 0; r < 4; ++r) {
                float zh = (z[tn][r] - mu4[r]) * rstd4[r];
                float tgt = b2f(vraw[tn * 4 + r]) - b2f(kraw[tn * 4 + r]);
                float dzh = (gd4[tn] * zh + bd4[tn] - tgt) * gd4[tn];
                gS[tn][r] = lr4[r] * ((dzh - m1[r] - zh * m2[r]) * rstd4[r]);
            }
        {  // gradS^T into LDS
            unsigned* g32 = (unsigned*)GST;
#pragma unroll
            for (int tn = 0; tn < 4; ++tn) {
                int a = (tn * 16 + col) * 20 + quad * 2;
                g32[a] = pk2(gS[tn][0], gS[tn][1]);
                g32[a + 1] = pk2(gS[tn][2], gS[tn][3]);
            }
        }

        // fragment reads
        bf16x8_t gsf[4], puf;
#pragma unroll
        for (int t = 0; t < 4; ++t)
            gsf[t] = *(const bf16x8_t*)&GST[(t * 16 + col) * 40 + quad * 8];
        puf = *(const bf16x8_t*)&PUL[col * 40 + quad * 8];

        // W update first (so the hoisted wbf read below has the epilogue to cover latency)
#pragma unroll
        for (int tm = 0; tm < 4; ++tm)
#pragma unroll
            for (int tn = 0; tn < 4; ++tn) {
                f32x4_t dw = __builtin_amdgcn_mfma_f32_16x16x32_bf16(xkf[tm], gsf[tn], zf, 0, 0, 0);
#pragma unroll
                for (int r = 0; r < 4; ++r) Wc[tm][tn][r] -= gs15 * dw[r];
            }
        {
            unsigned* wb32 = (unsigned*)WbL;
#pragma unroll
            for (int tn = 0; tn < 4; ++tn)
#pragma unroll
                for (int tm = 0; tm < 4; ++tm) {
                    int a = (tn * 16 + col) * 36 + tm * 8 + quad * 2;
                    wb32[a] = pk2(Wc[tm][tn][0], Wc[tm][tn][1]);
                    wb32[a + 1] = pk2(Wc[tm][tn][2], Wc[tm][tn][3]);
                }
        }

        // Z_bar = XQW + bb - gs[i] * (Pu @ gradS)   (reuse z as zbar)
#pragma unroll
        for (int tn = 0; tn < 4; ++tn) {
            f32x4_t pg = __builtin_amdgcn_mfma_f32_16x16x32_bf16(puf, gsf[tn], zf, 0, 0, 0);
#pragma unroll
            for (int r = 0; r < 4; ++r) z[tn][r] = xqw[tn][r] + bbv[tn] - gs4[r] * pg[r];
        }
        // y = XQ + ln_fwd(Z_bar)  -> bf16 (ys stored PERMUTED: ushort4 per r)
#pragma unroll
        for (int r = 0; r < 4; ++r) {
            float s1 = z[0][r] + z[1][r] + z[2][r] + z[3][r];
            float s2 = z[0][r] * z[0][r] + z[1][r] * z[1][r] + z[2][r] * z[2][r] + z[3][r] * z[3][r];
#pragma unroll
            for (int m = 1; m <= 8; m <<= 1) { s1 += __shfl_xor(s1, m); s2 += __shfl_xor(s2, m); }
            float mu = s1 * (1.f / 64.f);
            float var = s2 * (1.f / 64.f) - mu * mu;
            mu4[r] = mu;
            rstd4[r] = rsqrtf(var + 1e-5f);
        }
#pragma unroll
        for (int r = 0; r < 4; ++r) {
            ushort4 yv;
            float y0 = b2f(qraw[0 * 4 + r]) + gd4[0] * (z[0][r] - mu4[r]) * rstd4[r] + bd4[0];
            float y1 = b2f(qraw[1 * 4 + r]) + gd4[1] * (z[1][r] - mu4[r]) * rstd4[r] + bd4[1];
            float y2 = b2f(qraw[2 * 4 + r]) + gd4[2] * (z[2][r] - mu4[r]) * rstd4[r] + bd4[2];
            float y3 = b2f(qraw[3 * 4 + r]) + gd4[3] * (z[3][r] - mu4[r]) * rstd4[r] + bd4[3];
            yv.x = f2b(y0); yv.y = f2b(y1); yv.z = f2b(y2); yv.w = f2b(y3);
            *(ushort4*)(ys + (long)(b * SS + s0 + quad * 4 + r) * DD + h * 64 + col * 4) = yv;
        }

        // b update: bb -= gs15 * colsum(gradS)
#pragma unroll
        for (int tn = 0; tn < 4; ++tn) {
            float c = gS[tn][0] + gS[tn][1] + gS[tn][2] + gS[tn][3];
            c += __shfl_xor(c, 16);
            c += __shfl_xor(c, 32);
            bbv[tn] -= gs15 * c;
        }

        // hoisted: XKT(n+1) write from prefetched nkraw, then xkf(n+1) + wbf(n+1) reads
        {
            unsigned* x32 = (unsigned*)XKT;
#pragma unroll
            for (int tn = 0; tn < 4; ++tn) {
                int a = (tn * 16 + col) * 20 + quad * 2;
                x32[a] = pk2r(nkraw[tn * 4 + 0], nkraw[tn * 4 + 1]);
                x32[a + 1] = pk2r(nkraw[tn * 4 + 2], nkraw[tn * 4 + 3]);
            }
#pragma unroll
            for (int t = 0; t < 4; ++t)
                xkf[t] = *(const bf16x8_t*)&XKT[(t * 16 + col) * 40 + quad * 8];
#pragma unroll
            for (int tn = 0; tn < 4; ++tn)
#pragma unroll
                for (int kh = 0; kh < 2; ++kh)
                    wbf[tn][kh] = *(const bf16x8_t*)&WbL[(tn * 16 + col) * 72 + kh * 32 + quad * 8];
        }

        ka[0] = nka[0]; ka[1] = nka[1];
        qa[0] = nqa[0]; qa[1] = nqa[1];
#pragma unroll
        for (int r = 0; r < 4; ++r) lr4[r] = nlr[r];
#pragma unroll
        for (int j = 0; j < 16; ++j) { kraw[j] = nkraw[j]; vraw[j] = nvraw[j]; qraw[j] = nqraw[j]; }
    }
}

// ---------------- post layernorm (bf16 in, PERMUTED space) -> bf16 out (permuted) ----------------
// stats are permutation-invariant; gamma/beta passed pre-permuted (pgp/pbp)
__global__ __launch_bounds__(256) void k_postln(const u16* __restrict__ ys, const float* __restrict__ pg,
                                                const float* __restrict__ pb, u16* __restrict__ outb) {
    __shared__ float red[8];
    int row = blockIdx.x, tid = threadIdx.x, lane = tid & 63, wv = tid >> 6;
    const u16* rp = ys + row * 2048 + tid * 8;
    uint4 pkd = *(const uint4*)rp;
    float v[8];
    v[0] = b2f((u16)pkd.x); v[1] = b2f((u16)(pkd.x >> 16));
    v[2] = b2f((u16)pkd.y); v[3] = b2f((u16)(pkd.y >> 16));
    v[4] = b2f((u16)pkd.z); v[5] = b2f((u16)(pkd.z >> 16));
    v[6] = b2f((u16)pkd.w); v[7] = b2f((u16)(pkd.w >> 16));
    float s1 = 0.f, s2 = 0.f;
#pragma unroll
    for (int i = 0; i < 8; ++i) { s1 += v[i]; s2 += v[i] * v[i]; }
    s1 = wsum(s1);
    s2 = wsum(s2);
    if (lane == 0) {
        red[wv] = s1;
        red[wv + 4] = s2;
    }
    __syncthreads();
    float S1 = red[0] + red[1] + red[2] + red[3];
    float S2 = red[4] + red[5] + red[6] + red[7];
    float mu = S1 * (1.f / 2048), var = S2 * (1.f / 2048) - mu * mu;
    float rstd = rsqrtf(var + 1e-5f);
    const float4 g0 = *(const float4*)(pg + tid * 8);
    const float4 g1 = *(const float4*)(pg + tid * 8 + 4);
    const float4 b0v = *(const float4*)(pb + tid * 8);
    const float4 b1v = *(const float4*)(pb + tid * 8 + 4);
    float o[8];
    o[0] = g0.x * (v[0] - mu) * rstd + b0v.x;
    o[1] = g0.y * (v[1] - mu) * rstd + b0v.y;
    o[2] = g0.z * (v[2] - mu) * rstd + b0v.z;
    o[3] = g0.w * (v[3] - mu) * rstd + b0v.w;
    o[4] = g1.x * (v[4] - mu) * rstd + b1v.x;
    o[5] = g1.y * (v[5] - mu) * rstd + b1v.y;
    o[6] = g1.z * (v[6] - mu) * rstd + b1v.z;
    o[7] = g1.w * (v[7] - mu) * rstd + b1v.w;
    uint4 po;
    po.x = pk2(o[0], o[1]);
    po.y = pk2(o[2], o[3]);
    po.z = pk2(o[4], o[5]);
    po.w = pk2(o[6], o[7]);
    *(uint4*)(outb + row * 2048 + tid * 8) = po;
}

extern "C" void kernel_launch(void* const* d_in, const int* in_sizes, int n_in,
                              void* d_out, int out_size, void* d_ws, size_t ws_size,
                              hipStream_t stream) {
    const float* x = (const float*)d_in[0];
    const float* pf = (const float*)d_in[1];
    const float* Wq = (const float*)d_in[2];
    const float* Wk = (const float*)d_in[3];
    const float* Wv = (const float*)d_in[4];
    const float* Wo = (const float*)d_in[5];
    const float* pg = (const float*)d_in[6];
    const float* pb = (const float*)d_in[7];
    const float* ilrW = (const float*)d_in[8];
    const float* ilrb = (const float*)d_in[9];
    const float* lgs = (const float*)d_in[10];
    const float* tg = (const float*)d_in[11];
    const float* tb = (const float*)d_in[12];
    const float* W0 = (const float*)d_in[13];
    const float* b0 = (const float*)d_in[14];
    float* out = (float*)d_out;
    char* ws = (char*)d_ws;

    // workspace layout
    u16* xbf = (u16*)(ws + 0);             // 16 MB  (reused: kc after k_lr, lnb after scan)
    u16* wqb = (u16*)(ws + 16777216);      // 8 MB   (reused as qc[0:8MB] after gemm<1>)
    u16* wkb = (u16*)(ws + 25165824);      // 8 MB   (reused as qc[8:16MB] after gemm<1>)
    u16* wvb = (u16*)(ws + 33554432);      // 8 MB
    u16* wob = (u16*)(ws + 41943040);      // 8 MB   (permuted k-columns)
    u16* qbuf = (u16*)(ws + 50331648);     // 16 MB  (std layout, RoPE'd)
    u16* kbuf = (u16*)(ws + 67108864);     // 16 MB  (std layout, RoPE'd)
    u16* vbuf = (u16*)(ws + 83886080);     // 16 MB  (PERMUTED layout, RoPE'd)
    float* ct = (float*)(ws + 100663296);  // 256 KB
    float* st = (float*)(ws + 100925440);  // 256 KB
    float* lrb = (float*)(ws + 101187584); // 512 KB
    u16* ysb = (u16*)(ws + 101711872);     // 16 MB (bf16, permuted space)
    float* pgp = (float*)(ws + 118489088); // 8 KB
    float* pbp = (float*)(ws + 118497280); // 8 KB
    u16* qc = (u16*)(ws + 16777216);       // 16 MB perm q (over dead wqb+wkb)
    u16* kc = (u16*)(ws + 0);              // 16 MB perm k (over dead xbf, after k_lr)
    u16* lnb = (u16*)(ws + 0);             // reuse (dead kc after scan)

    k_cvt5<<<dim3(4096, 6), 256, 0, stream>>>(x, Wq, Wk, Wv, Wo, xbf, wqb, wkb, wvb, wob);
    k_trig<<<256, 256, 0, stream>>>(pf, ct, st);
    k_ppg<<<8, 256, 0, stream>>>(pg, pb, pgp, pbp);

    k_gemm_bt<1><<<dim3(16, 32, 3), 256, 0, stream>>>(xbf, wqb, wkb, wvb, qbuf, kbuf, vbuf,
                                                      4096, 2048, 2048, ct, st);

    k_lr<<<1024, 256, 0, stream>>>(xbf, ilrW, ilrb, lrb);

    k_prep<<<dim3(512, 2), 256, 0, stream>>>(qbuf, kbuf, qc, kc);

    k_scan<<<64, 64, 0, stream>>>(qbuf, kbuf, qc, kc, vbuf, lrb, lgs, tg, tb, W0, b0, ysb);

    k_postln<<<4096, 256, 0, stream>>>(ysb, pgp, pbp, lnb);
    k_gemm_bt<0><<<dim3(16, 32, 1), 256, 0, stream>>>(lnb, wob, wob, wob, out, out, out,
                                                      4096, 2048, 2048, nullptr, nullptr);
}

// Round 4
// 798.552 us; speedup vs baseline: 1.5216x; 1.0973x over previous
//
#include <hip/hip_runtime.h>
#include <hip/hip_bf16.h>
#include <math.h>

// Problem constants
#define BB 2
#define SS 2048
#define DD 2048
#define HH 32
#define HDD 64
#define MBB 16
#define NN 128

typedef unsigned short u16;
typedef short bf16x8_t __attribute__((ext_vector_type(8)));
typedef float f32x4_t __attribute__((ext_vector_type(4)));

__device__ __forceinline__ float b2f(u16 u) { return __uint_as_float(((unsigned)u) << 16); }
__device__ __forceinline__ u16 f2b(float f) {
    unsigned u = __float_as_uint(f);
    return (u16)((u + 0x7FFFu + ((u >> 16) & 1u)) >> 16);
}
__device__ __forceinline__ unsigned pk2(float a, float b) {
    return (unsigned)f2b(a) | ((unsigned)f2b(b) << 16);
}
// HW packed f32->bf16 (RNE, same rounding as f2b) — 1 instr instead of ~10
__device__ __forceinline__ unsigned cvtpk(float lo, float hi) {
    unsigned r;
    asm("v_cvt_pk_bf16_f32 %0, %1, %2" : "=v"(r) : "v"(lo), "v"(hi));
    return r;
}
__device__ __forceinline__ unsigned pk2r(u16 a, u16 b) { return (unsigned)a | ((unsigned)b << 16); }
__device__ __forceinline__ float wsum(float x) {
    x += __shfl_xor(x, 32);
    x += __shfl_xor(x, 16);
    x += __shfl_xor(x, 8);
    x += __shfl_xor(x, 4);
    x += __shfl_xor(x, 2);
    x += __shfl_xor(x, 1);
    return x;
}

typedef __attribute__((address_space(3))) unsigned int lds_u32;
typedef __attribute__((address_space(1))) const unsigned int glb_u32;
__device__ __forceinline__ void async_copy16(const void* g, void* l) {
    __builtin_amdgcn_global_load_lds((glb_u32*)g, (lds_u32*)l, 16, 0, 0);
}

// within-head permutation: perm(d) = (d&15)*4 + (d>>4);  inverse: d = (j>>2) + (j&3)*16

// ---------------- fused fp32 -> bf16 for x + 4 weight matrices ----------------
// grid (4096, 6): slice 0,1 = x halves; 2..5 = Wq,Wk,Wv,Wo. 4194304 elems/slice.
// Wo (slice 5) stored with permuted k-columns to match permuted lnb (joint k-perm is GEMM-invariant).
__global__ __launch_bounds__(256) void k_cvt5(const float* __restrict__ x, const float* __restrict__ wq,
                                              const float* __restrict__ wk, const float* __restrict__ wv,
                                              const float* __restrict__ wo, u16* __restrict__ xb,
                                              u16* __restrict__ wqb, u16* __restrict__ wkb,
                                              u16* __restrict__ wvb, u16* __restrict__ wob) {
    int sl = blockIdx.y;
    long e = (long)(blockIdx.x * 256 + threadIdx.x) * 4;
    if (sl == 5) {
        long n = e >> 11;
        int cin = (int)(e & 2047);
        int hd0 = (cin >> 6) * 64 + ((cin & 63) >> 2);
        const float* src = wo + n * 2048 + hd0;
        float f0 = src[0], f1 = src[16], f2 = src[32], f3 = src[48];
        uint2 o;
        o.x = pk2(f0, f1);
        o.y = pk2(f2, f3);
        *(uint2*)(wob + e) = o;
        return;
    }
    const float* s;
    u16* d;
    if (sl == 0) { s = x; d = xb; }
    else if (sl == 1) { s = x + 4194304; d = xb + 4194304; }
    else if (sl == 2) { s = wq; d = wqb; }
    else if (sl == 3) { s = wk; d = wkb; }
    else { s = wv; d = wvb; }
    float4 f = *(const float4*)(s + e);
    uint2 o;
    o.x = pk2(f.x, f.y);
    o.y = pk2(f.z, f.w);
    *(uint2*)(d + e) = o;
}

// ---------------- cos/sin tables ----------------
__global__ void k_trig(const float* __restrict__ pf, float* __restrict__ ct, float* __restrict__ st) {
    int i = blockIdx.x * 256 + threadIdx.x;  // 65536 = S*32
    float f = pf[i];
    ct[i] = cosf(f);
    st[i] = sinf(f);
}

// ---------------- permuted post-LN gamma/beta ----------------
__global__ void k_ppg(const float* __restrict__ pg, const float* __restrict__ pb,
                      float* __restrict__ pgp, float* __restrict__ pbp) {
    int i = blockIdx.x * 256 + threadIdx.x;  // 2048
    int h = i >> 6, o = i & 63;
    int src = h * 64 + (o >> 2) + (o & 3) * 16;
    pgp[i] = pg[src];
    pbp[i] = pb[src];
}

// ---------------- bf16 MFMA GEMM:  C[M,N] = A[M,K] * B[N,K]^T ----------------
// EPI 0: store fp32 row-major; EPI 1: RoPE, bf16 (B,H,S,HD); z==2 (V) stores within-head permuted
template <int EPI>
__global__ __launch_bounds__(256) void k_gemm_bt(const u16* __restrict__ A, const u16* __restrict__ B0,
                                                 const u16* __restrict__ B1, const u16* __restrict__ B2,
                                                 void* __restrict__ C0, void* __restrict__ C1,
                                                 void* __restrict__ C2, int M, int Nn, int K,
                                                 const float* __restrict__ ct, const float* __restrict__ st) {
    __shared__ u16 As[128 * 32];
    __shared__ u16 Bs[128 * 32];
    int z = blockIdx.z;
    const u16* Bm = (z == 0) ? B0 : (z == 1) ? B1 : B2;
    void* Cout = (z == 0) ? C0 : (z == 1) ? C1 : C2;
    int tid = threadIdx.x, lane = tid & 63, wv = tid >> 6;
    int m0 = blockIdx.y * 128, n0 = blockIdx.x * 128;
    int wm = wv >> 1, wn = wv & 1;

    f32x4_t acc[4][4];
    f32x4_t zero = {0.f, 0.f, 0.f, 0.f};
#pragma unroll
    for (int a = 0; a < 4; ++a)
#pragma unroll
        for (int b = 0; b < 4; ++b) acc[a][b] = zero;

    int mrow = lane & 15, qk = (lane >> 4) * 8;
    const int kTiles = K >> 5;
    for (int kt = 0; kt < kTiles; ++kt) {
        __syncthreads();
        int kb = kt << 5;
#pragma unroll
        for (int it = 0; it < 2; ++it) {
            int cb = it * 256 + wv * 64;  // wave-uniform chunk base
            int c = cb + lane;
            const u16* gpA = A + (m0 + (c >> 2)) * K + kb + ((c & 3) << 3);
            async_copy16(gpA, &As[cb << 3]);
            const u16* gpB = Bm + (n0 + (c >> 2)) * K + kb + ((c & 3) << 3);
            async_copy16(gpB, &Bs[cb << 3]);
        }
        asm volatile("s_waitcnt vmcnt(0)" ::: "memory");
        __syncthreads();

        bf16x8_t af[4], bfr[4];
#pragma unroll
        for (int mi = 0; mi < 4; ++mi)
            af[mi] = *(const bf16x8_t*)&As[(wm * 64 + mi * 16 + mrow) * 32 + qk];
#pragma unroll
        for (int ni = 0; ni < 4; ++ni)
            bfr[ni] = *(const bf16x8_t*)&Bs[(wn * 64 + ni * 16 + mrow) * 32 + qk];
#pragma unroll
        for (int mi = 0; mi < 4; ++mi)
#pragma unroll
            for (int ni = 0; ni < 4; ++ni)
                acc[mi][ni] = __builtin_amdgcn_mfma_f32_16x16x32_bf16(af[mi], bfr[ni], acc[mi][ni], 0, 0, 0);
    }

    int col16 = lane & 15, rq = (lane >> 4) * 4;
#pragma unroll
    for (int mi = 0; mi < 4; ++mi) {
#pragma unroll
        for (int ni = 0; ni < 4; ++ni) {
#pragma unroll
            for (int r = 0; r < 4; ++r) {
                int gr = m0 + wm * 64 + mi * 16 + rq + r;
                int gc = n0 + wn * 64 + ni * 16 + col16;
                float val = acc[mi][ni][r];
                if (EPI == 0) {
                    ((float*)Cout)[gr * Nn + gc] = val;
                } else {
                    // fused RoPE: pair partner sits on lane^1 (gc differs in bit 0)
                    int b = gr >> 11, s2 = gr & 2047, hh = gc >> 6, hd = gc & 63;
                    int fi = s2 * 32 + (hd >> 1);
                    float c = ct[fi], sn = st[fi];
                    float partner = __shfl_xor(val, 1);
                    float y = (gc & 1) ? (partner * sn + val * c) : (val * c - partner * sn);
                    int po = (z == 2) ? ((hd & 15) * 4 + (hd >> 4)) : hd;  // V stored permuted
                    ((u16*)Cout)[(((b * HH + hh) * SS) + s2) * HDD + po] = f2b(y);
                }
            }
        }
    }
}

// ---------------- ilr gate ----------------
__global__ __launch_bounds__(256) void k_lr(const u16* __restrict__ xb, const float* __restrict__ ilrW,
                                            const float* __restrict__ ilrb, float* __restrict__ lrout) {
    __shared__ u16 xr[4][2048];
    int row0 = blockIdx.x * 4;
    int tid = threadIdx.x, lane = tid & 63, wv = tid >> 6;
    const unsigned* src = (const unsigned*)(xb + row0 * 2048);
    unsigned* dst = (unsigned*)xr;
    for (int i = tid; i < 4096; i += 256) dst[i] = src[i];
    __syncthreads();
    int b = row0 >> 11, s0 = row0 & 2047;
#pragma unroll
    for (int sub = 0; sub < 8; ++sub) {
        int h = wv * 8 + sub;
        const float* wp = ilrW + h * 2048;
        float a0 = 0.f, a1 = 0.f, a2 = 0.f, a3 = 0.f;
        for (int i = 0; i < 16; ++i) {
            int idx = i * 128 + lane * 2;
            float2 w2 = *(const float2*)(wp + idx);
            unsigned p0 = *(const unsigned*)&xr[0][idx];
            unsigned p1 = *(const unsigned*)&xr[1][idx];
            unsigned p2 = *(const unsigned*)&xr[2][idx];
            unsigned p3 = *(const unsigned*)&xr[3][idx];
            a0 += b2f((u16)p0) * w2.x + b2f((u16)(p0 >> 16)) * w2.y;
            a1 += b2f((u16)p1) * w2.x + b2f((u16)(p1 >> 16)) * w2.y;
            a2 += b2f((u16)p2) * w2.x + b2f((u16)(p2 >> 16)) * w2.y;
            a3 += b2f((u16)p3) * w2.x + b2f((u16)(p3 >> 16)) * w2.y;
        }
        a0 = wsum(a0);
        a1 = wsum(a1);
        a2 = wsum(a2);
        a3 = wsum(a3);
        if (lane == 0) {
            float bv = ilrb[h];
            float* op = lrout + ((b * HH + h) * SS) + s0;
            op[0] = (1.0f / (1.0f + expf(-(a0 + bv)))) * (1.0f / 64.0f);
            op[1] = (1.0f / (1.0f + expf(-(a1 + bv)))) * (1.0f / 64.0f);
            op[2] = (1.0f / (1.0f + expf(-(a2 + bv)))) * (1.0f / 64.0f);
            op[3] = (1.0f / (1.0f + expf(-(a3 + bv)))) * (1.0f / 64.0f);
        }
    }
}

// ---------------- TTT scan: ONE WAVE per (b,h) ----------------
// Latency-bound (wall time = 128 * per-step critical path). This version attacks the path:
//  * v_cvt_pk_bf16_f32 for all f32->bf16 packs (Wb 32, GST 8, ys 8) — ~380 fewer VALU/step
//  * ln_l2_bwd's two serial 4-hop shuffle phases fused into ONE via algebraic expansion:
//    m1,m2 derived from {Σz, Σz², Σg²z, Σg²z², Σc1·z, Σc1}, c1 = g·(b - tgt)
//  * permuted V/ys (vector loads/stores); q/k read direct (vectorizing them measured 0)
__global__ __launch_bounds__(64, 1) void k_scan(const u16* __restrict__ qb, const u16* __restrict__ kb2,
                                                const u16* __restrict__ vc, const float* __restrict__ lrbuf,
                                                const float* __restrict__ lgs, const float* __restrict__ tg,
                                                const float* __restrict__ tb, const float* __restrict__ W0,
                                                const float* __restrict__ b0, u16* __restrict__ ys) {
    __shared__ u16 WbL[64 * 72];  // [d2][d1]
    __shared__ u16 XKT[64 * 40];  // [d1][j(32)]  j>=16 stays 0
    __shared__ u16 GST[64 * 40];  // [d2][j(32)]  j>=16 stays 0
    __shared__ u16 PUL[16 * 40];  // [i][j(32)]   j>=16 stays 0 (bf16)

    const int bh = blockIdx.x, h = bh & 31, b = bh >> 5;
    const int lane = threadIdx.x & 63;
    const int quad = lane >> 4, col = lane & 15;
    const int base = bh * SS;

    {  // zero-init (upper j-halves must stay zero forever)
        unsigned* p1 = (unsigned*)XKT;
        unsigned* p2 = (unsigned*)GST;
        unsigned* p3 = (unsigned*)PUL;
        for (int i = lane; i < 1280; i += 64) { p1[i] = 0; p2[i] = 0; }
        for (int i = lane; i < 320; i += 64) p3[i] = 0;
    }

    float gd4[4], bd4[4], bbv[4], g2[4], gb[4];
#pragma unroll
    for (int tn = 0; tn < 4; ++tn) {
        gd4[tn] = tg[h * 64 + tn * 16 + col];
        bd4[tn] = tb[h * 64 + tn * 16 + col];
        bbv[tn] = b0[h * 64 + tn * 16 + col];
        g2[tn] = gd4[tn] * gd4[tn];
        gb[tn] = gd4[tn] * bd4[tn];
    }
    float G2m;  // mean over d of gamma^2 (per-head constant)
    {
        float s = g2[0] + g2[1] + g2[2] + g2[3];
#pragma unroll
        for (int m = 1; m <= 8; m <<= 1) s += __shfl_xor(s, m);
        G2m = s * (1.f / 64.f);
    }
    float gs4[4];
#pragma unroll
    for (int r = 0; r < 4; ++r) {
        int i = quad * 4 + r;
        gs4[r] = fmaxf(1.f / (float)(i + 1) + lgs[i], 0.f);
    }
    const float gs15 = fmaxf(1.f / 16.f + lgs[15], 0.f);

    f32x4_t Wc[4][4];
#pragma unroll
    for (int tm = 0; tm < 4; ++tm)
#pragma unroll
        for (int tn = 0; tn < 4; ++tn)
#pragma unroll
            for (int r = 0; r < 4; ++r)
                Wc[tm][tn][r] = W0[h * 4096 + (tm * 16 + quad * 4 + r) * 64 + tn * 16 + col];

    {  // initial Wb
        unsigned* wb32 = (unsigned*)WbL;
#pragma unroll
        for (int tn = 0; tn < 4; ++tn)
#pragma unroll
            for (int tm = 0; tm < 4; ++tm) {
                int a = (tn * 16 + col) * 36 + tm * 8 + quad * 2;  // u32 units; row stride 36 u32
                wb32[a] = cvtpk(Wc[tm][tn][0], Wc[tm][tn][1]);
                wb32[a + 1] = cvtpk(Wc[tm][tn][2], Wc[tm][tn][3]);
            }
    }

    // prefetch chunk 0
    bf16x8_t ka[2], qa[2];
    float lr4[4];
    u16 kraw[16], vraw[16], qraw[16];
    {
        const u16* kp = kb2 + (base + col) * 64;
        const u16* qp = qb + (base + col) * 64;
#pragma unroll
        for (int kh = 0; kh < 2; ++kh) {
            ka[kh] = *(const bf16x8_t*)(kp + kh * 32 + quad * 8);
            qa[kh] = *(const bf16x8_t*)(qp + kh * 32 + quad * 8);
        }
#pragma unroll
        for (int r = 0; r < 4; ++r) lr4[r] = lrbuf[base + quad * 4 + r];
#pragma unroll
        for (int tn = 0; tn < 4; ++tn)
#pragma unroll
            for (int r = 0; r < 4; ++r) {
                int idx = (base + quad * 4 + r) * 64 + tn * 16 + col;
                kraw[tn * 4 + r] = kb2[idx];
                qraw[tn * 4 + r] = qb[idx];
            }
#pragma unroll
        for (int r = 0; r < 4; ++r) {
            long ro = (long)(base + quad * 4 + r) * 64 + col * 4;
            ushort4 tv = *(const ushort4*)(vc + ro);
            vraw[r] = tv.x; vraw[4 + r] = tv.y; vraw[8 + r] = tv.z; vraw[12 + r] = tv.w;
        }
    }

    // prologue: XKT(0) write + xkf(0) read; wbf(0) read
    bf16x8_t xkf[4], wbf[4][2];
    {
        unsigned* x32 = (unsigned*)XKT;
#pragma unroll
        for (int tn = 0; tn < 4; ++tn) {
            int a = (tn * 16 + col) * 20 + quad * 2;
            x32[a] = pk2r(kraw[tn * 4 + 0], kraw[tn * 4 + 1]);
            x32[a + 1] = pk2r(kraw[tn * 4 + 2], kraw[tn * 4 + 3]);
        }
#pragma unroll
        for (int t = 0; t < 4; ++t)
            xkf[t] = *(const bf16x8_t*)&XKT[(t * 16 + col) * 40 + quad * 8];
#pragma unroll
        for (int tn = 0; tn < 4; ++tn)
#pragma unroll
            for (int kh = 0; kh < 2; ++kh)
                wbf[tn][kh] = *(const bf16x8_t*)&WbL[(tn * 16 + col) * 72 + kh * 32 + quad * 8];
    }

    const f32x4_t zf = {0.f, 0.f, 0.f, 0.f};

    for (int n = 0; n < NN; ++n) {
        const int s0 = n * 16;

        // Z = XK@W, XQW = XQ@W, Attn = XQ@XK^T  (operands all in regs)
        f32x4_t z[4], xqw[4], attn;
#pragma unroll
        for (int tn = 0; tn < 4; ++tn) {
            z[tn] = __builtin_amdgcn_mfma_f32_16x16x32_bf16(ka[1], wbf[tn][1], zf, 0, 0, 0);
            z[tn] = __builtin_amdgcn_mfma_f32_16x16x32_bf16(ka[0], wbf[tn][0], z[tn], 0, 0, 0);
            xqw[tn] = __builtin_amdgcn_mfma_f32_16x16x32_bf16(qa[1], wbf[tn][1], zf, 0, 0, 0);
            xqw[tn] = __builtin_amdgcn_mfma_f32_16x16x32_bf16(qa[0], wbf[tn][0], xqw[tn], 0, 0, 0);
        }
        attn = __builtin_amdgcn_mfma_f32_16x16x32_bf16(qa[1], ka[1], zf, 0, 0, 0);
        attn = __builtin_amdgcn_mfma_f32_16x16x32_bf16(qa[0], ka[0], attn, 0, 0, 0);

        // Pu = tril(1 + Attn) -> LDS early
#pragma unroll
        for (int r = 0; r < 4; ++r) {
            float pv = (col <= quad * 4 + r) ? (1.f + attn[r]) : 0.f;
            PUL[(quad * 4 + r) * 40 + col] = f2b(pv);
        }

        // prefetch next chunk (clamped on last iter)
        bf16x8_t nka[2], nqa[2];
        float nlr[4];
        u16 nkraw[16], nvraw[16], nqraw[16];
        {
            const int sp = (n + 1 < NN) ? s0 + 16 : s0;
            const u16* kp = kb2 + (base + sp + col) * 64;
            const u16* qp = qb + (base + sp + col) * 64;
#pragma unroll
            for (int kh = 0; kh < 2; ++kh) {
                nka[kh] = *(const bf16x8_t*)(kp + kh * 32 + quad * 8);
                nqa[kh] = *(const bf16x8_t*)(qp + kh * 32 + quad * 8);
            }
#pragma unroll
            for (int r = 0; r < 4; ++r) nlr[r] = lrbuf[base + sp + quad * 4 + r];
#pragma unroll
            for (int tn = 0; tn < 4; ++tn)
#pragma unroll
                for (int r = 0; r < 4; ++r) {
                    int idx = (base + sp + quad * 4 + r) * 64 + tn * 16 + col;
                    nkraw[tn * 4 + r] = kb2[idx];
                    nqraw[tn * 4 + r] = qb[idx];
                }
#pragma unroll
            for (int r = 0; r < 4; ++r) {
                long ro = (long)(base + sp + quad * 4 + r) * 64 + col * 4;
                ushort4 tv = *(const ushort4*)(vc + ro);
                nvraw[r] = tv.x; nvraw[4 + r] = tv.y; nvraw[8 + r] = tv.z; nvraw[12 + r] = tv.w;
            }
        }

        // Z += bb ; fused ln_l2_bwd: single reduce phase over 6 sums
#pragma unroll
        for (int tn = 0; tn < 4; ++tn)
#pragma unroll
            for (int r = 0; r < 4; ++r) z[tn][r] += bbv[tn];

        float c1[16];
        float A1[4], A2[4], A3[4], A4[4], A5[4], A6[4];
#pragma unroll
        for (int r = 0; r < 4; ++r) { A1[r] = 0.f; A2[r] = 0.f; A3[r] = 0.f; A4[r] = 0.f; A5[r] = 0.f; A6[r] = 0.f; }
#pragma unroll
        for (int tn = 0; tn < 4; ++tn)
#pragma unroll
            for (int r = 0; r < 4; ++r) {
                float zv = z[tn][r];
                float tgt = b2f(vraw[tn * 4 + r]) - b2f(kraw[tn * 4 + r]);
                float c = gb[tn] - gd4[tn] * tgt;  // g*(b - tgt)
                c1[tn * 4 + r] = c;
                float t = g2[tn] * zv;
                A1[r] += zv;
                A2[r] = fmaf(zv, zv, A2[r]);
                A3[r] += t;
                A4[r] = fmaf(t, zv, A4[r]);
                A5[r] = fmaf(c, zv, A5[r]);
                A6[r] += c;
            }
#pragma unroll
        for (int m = 1; m <= 8; m <<= 1) {
#pragma unroll
            for (int r = 0; r < 4; ++r) {
                A1[r] += __shfl_xor(A1[r], m);
                A2[r] += __shfl_xor(A2[r], m);
                A3[r] += __shfl_xor(A3[r], m);
                A4[r] += __shfl_xor(A4[r], m);
                A5[r] += __shfl_xor(A5[r], m);
                A6[r] += __shfl_xor(A6[r], m);
            }
        }
        float mu4[4], rstd4[4], m1[4], m2[4], rl[4];
#pragma unroll
        for (int r = 0; r < 4; ++r) {
            float mu = A1[r] * (1.f / 64.f);
            float var = A2[r] * (1.f / 64.f) - mu * mu;
            float rstd = rsqrtf(var + 1e-5f);
            float T1m = A3[r] * (1.f / 64.f);
            float T2m = A4[r] * (1.f / 64.f);
            float T3m = A5[r] * (1.f / 64.f);
            float C1m = A6[r] * (1.f / 64.f);
            m1[r] = rstd * (T1m - mu * G2m) + C1m;
            m2[r] = rstd * rstd * (T2m - 2.f * mu * T1m + mu * mu * G2m) + rstd * (T3m - mu * C1m);
            mu4[r] = mu;
            rstd4[r] = rstd;
            rl[r] = rstd * lr4[r];
        }
        float gS[4][4];  // lr[j] * grad[j][d]  (C-layout)
#pragma unroll
        for (int tn = 0; tn < 4; ++tn)
#pragma unroll
            for (int r = 0; r < 4; ++r) {
                float zh = (z[tn][r] - mu4[r]) * rstd4[r];
                float dzh = fmaf(g2[tn], zh, c1[tn * 4 + r]);
                gS[tn][r] = fmaf(-m2[r], zh, dzh - m1[r]) * rl[r];
            }
        {  // gradS^T into LDS
            unsigned* g32 = (unsigned*)GST;
#pragma unroll
            for (int tn = 0; tn < 4; ++tn) {
                int a = (tn * 16 + col) * 20 + quad * 2;
                g32[a] = cvtpk(gS[tn][0], gS[tn][1]);
                g32[a + 1] = cvtpk(gS[tn][2], gS[tn][3]);
            }
        }

        // fragment reads
        bf16x8_t gsf[4], puf;
#pragma unroll
        for (int t = 0; t < 4; ++t)
            gsf[t] = *(const bf16x8_t*)&GST[(t * 16 + col) * 40 + quad * 8];
        puf = *(const bf16x8_t*)&PUL[col * 40 + quad * 8];

        // W update first (hoisted wbf read below gets the epilogue to cover latency)
#pragma unroll
        for (int tm = 0; tm < 4; ++tm)
#pragma unroll
            for (int tn = 0; tn < 4; ++tn) {
                f32x4_t dw = __builtin_amdgcn_mfma_f32_16x16x32_bf16(xkf[tm], gsf[tn], zf, 0, 0, 0);
#pragma unroll
                for (int r = 0; r < 4; ++r) Wc[tm][tn][r] -= gs15 * dw[r];
            }
        {
            unsigned* wb32 = (unsigned*)WbL;
#pragma unroll
            for (int tn = 0; tn < 4; ++tn)
#pragma unroll
                for (int tm = 0; tm < 4; ++tm) {
                    int a = (tn * 16 + col) * 36 + tm * 8 + quad * 2;
                    wb32[a] = cvtpk(Wc[tm][tn][0], Wc[tm][tn][1]);
                    wb32[a + 1] = cvtpk(Wc[tm][tn][2], Wc[tm][tn][3]);
                }
        }

        // Z_bar = XQW + bb - gs[i] * (Pu @ gradS)
#pragma unroll
        for (int tn = 0; tn < 4; ++tn) {
            f32x4_t pg = __builtin_amdgcn_mfma_f32_16x16x32_bf16(puf, gsf[tn], zf, 0, 0, 0);
#pragma unroll
            for (int r = 0; r < 4; ++r) z[tn][r] = xqw[tn][r] + bbv[tn] - gs4[r] * pg[r];
        }
        // y = XQ + ln_fwd(Z_bar)  -> bf16 (permuted layout, uint2 store)
#pragma unroll
        for (int r = 0; r < 4; ++r) {
            float s1 = z[0][r] + z[1][r] + z[2][r] + z[3][r];
            float s2 = z[0][r] * z[0][r] + z[1][r] * z[1][r] + z[2][r] * z[2][r] + z[3][r] * z[3][r];
#pragma unroll
            for (int m = 1; m <= 8; m <<= 1) { s1 += __shfl_xor(s1, m); s2 += __shfl_xor(s2, m); }
            float mu = s1 * (1.f / 64.f);
            float var = s2 * (1.f / 64.f) - mu * mu;
            mu4[r] = mu;
            rstd4[r] = rsqrtf(var + 1e-5f);
        }
#pragma unroll
        for (int r = 0; r < 4; ++r) {
            float y0 = b2f(qraw[0 * 4 + r]) + gd4[0] * (z[0][r] - mu4[r]) * rstd4[r] + bd4[0];
            float y1 = b2f(qraw[1 * 4 + r]) + gd4[1] * (z[1][r] - mu4[r]) * rstd4[r] + bd4[1];
            float y2 = b2f(qraw[2 * 4 + r]) + gd4[2] * (z[2][r] - mu4[r]) * rstd4[r] + bd4[2];
            float y3 = b2f(qraw[3 * 4 + r]) + gd4[3] * (z[3][r] - mu4[r]) * rstd4[r] + bd4[3];
            uint2 po;
            po.x = cvtpk(y0, y1);
            po.y = cvtpk(y2, y3);
            *(uint2*)(ys + (long)(b * SS + s0 + quad * 4 + r) * DD + h * 64 + col * 4) = po;
        }

        // b update: bb -= gs15 * colsum(gradS)
#pragma unroll
        for (int tn = 0; tn < 4; ++tn) {
            float c = gS[tn][0] + gS[tn][1] + gS[tn][2] + gS[tn][3];
            c += __shfl_xor(c, 16);
            c += __shfl_xor(c, 32);
            bbv[tn] -= gs15 * c;
        }

        // hoisted: XKT(n+1) write from prefetched nkraw, then xkf(n+1) + wbf(n+1) reads
        {
            unsigned* x32 = (unsigned*)XKT;
#pragma unroll
            for (int tn = 0; tn < 4; ++tn) {
                int a = (tn * 16 + col) * 20 + quad * 2;
                x32[a] = pk2r(nkraw[tn * 4 + 0], nkraw[tn * 4 + 1]);
                x32[a + 1] = pk2r(nkraw[tn * 4 + 2], nkraw[tn * 4 + 3]);
            }
#pragma unroll
            for (int t = 0; t < 4; ++t)
                xkf[t] = *(const bf16x8_t*)&XKT[(t * 16 + col) * 40 + quad * 8];
#pragma unroll
            for (int tn = 0; tn < 4; ++tn)
#pragma unroll
                for (int kh = 0; kh < 2; ++kh)
                    wbf[tn][kh] = *(const bf16x8_t*)&WbL[(tn * 16 + col) * 72 + kh * 32 + quad * 8];
        }

        ka[0] = nka[0]; ka[1] = nka[1];
        qa[0] = nqa[0]; qa[1] = nqa[1];
#pragma unroll
        for (int r = 0; r < 4; ++r) lr4[r] = nlr[r];
#pragma unroll
        for (int j = 0; j < 16; ++j) { kraw[j] = nkraw[j]; vraw[j] = nvraw[j]; qraw[j] = nqraw[j]; }
    }
}

// ---------------- post layernorm (bf16 in, PERMUTED space) -> bf16 out (permuted) ----------------
__global__ __launch_bounds__(256) void k_postln(const u16* __restrict__ ys, const float* __restrict__ pg,
                                                const float* __restrict__ pb, u16* __restrict__ outb) {
    __shared__ float red[8];
    int row = blockIdx.x, tid = threadIdx.x, lane = tid & 63, wv = tid >> 6;
    const u16* rp = ys + row * 2048 + tid * 8;
    uint4 pkd = *(const uint4*)rp;
    float v[8];
    v[0] = b2f((u16)pkd.x); v[1] = b2f((u16)(pkd.x >> 16));
    v[2] = b2f((u16)pkd.y); v[3] = b2f((u16)(pkd.y >> 16));
    v[4] = b2f((u16)pkd.z); v[5] = b2f((u16)(pkd.z >> 16));
    v[6] = b2f((u16)pkd.w); v[7] = b2f((u16)(pkd.w >> 16));
    float s1 = 0.f, s2 = 0.f;
#pragma unroll
    for (int i = 0; i < 8; ++i) { s1 += v[i]; s2 += v[i] * v[i]; }
    s1 = wsum(s1);
    s2 = wsum(s2);
    if (lane == 0) {
        red[wv] = s1;
        red[wv + 4] = s2;
    }
    __syncthreads();
    float S1 = red[0] + red[1] + red[2] + red[3];
    float S2 = red[4] + red[5] + red[6] + red[7];
    float mu = S1 * (1.f / 2048), var = S2 * (1.f / 2048) - mu * mu;
    float rstd = rsqrtf(var + 1e-5f);
    const float4 g0 = *(const float4*)(pg + tid * 8);
    const float4 g1 = *(const float4*)(pg + tid * 8 + 4);
    const float4 b0v = *(const float4*)(pb + tid * 8);
    const float4 b1v = *(const float4*)(pb + tid * 8 + 4);
    float o[8];
    o[0] = g0.x * (v[0] - mu) * rstd + b0v.x;
    o[1] = g0.y * (v[1] - mu) * rstd + b0v.y;
    o[2] = g0.z * (v[2] - mu) * rstd + b0v.z;
    o[3] = g0.w * (v[3] - mu) * rstd + b0v.w;
    o[4] = g1.x * (v[4] - mu) * rstd + b1v.x;
    o[5] = g1.y * (v[5] - mu) * rstd + b1v.y;
    o[6] = g1.z * (v[6] - mu) * rstd + b1v.z;
    o[7] = g1.w * (v[7] - mu) * rstd + b1v.w;
    uint4 po;
    po.x = pk2(o[0], o[1]);
    po.y = pk2(o[2], o[3]);
    po.z = pk2(o[4], o[5]);
    po.w = pk2(o[6], o[7]);
    *(uint4*)(outb + row * 2048 + tid * 8) = po;
}

extern "C" void kernel_launch(void* const* d_in, const int* in_sizes, int n_in,
                              void* d_out, int out_size, void* d_ws, size_t ws_size,
                              hipStream_t stream) {
    const float* x = (const float*)d_in[0];
    const float* pf = (const float*)d_in[1];
    const float* Wq = (const float*)d_in[2];
    const float* Wk = (const float*)d_in[3];
    const float* Wv = (const float*)d_in[4];
    const float* Wo = (const float*)d_in[5];
    const float* pg = (const float*)d_in[6];
    const float* pb = (const float*)d_in[7];
    const float* ilrW = (const float*)d_in[8];
    const float* ilrb = (const float*)d_in[9];
    const float* lgs = (const float*)d_in[10];
    const float* tg = (const float*)d_in[11];
    const float* tb = (const float*)d_in[12];
    const float* W0 = (const float*)d_in[13];
    const float* b0 = (const float*)d_in[14];
    float* out = (float*)d_out;
    char* ws = (char*)d_ws;

    // workspace layout
    u16* xbf = (u16*)(ws + 0);             // 16 MB  (reused as lnb later)
    u16* wqb = (u16*)(ws + 16777216);      // 8 MB
    u16* wkb = (u16*)(ws + 25165824);      // 8 MB
    u16* wvb = (u16*)(ws + 33554432);      // 8 MB
    u16* wob = (u16*)(ws + 41943040);      // 8 MB   (permuted k-columns)
    u16* qbuf = (u16*)(ws + 50331648);     // 16 MB  (std layout, RoPE'd)
    u16* kbuf = (u16*)(ws + 67108864);     // 16 MB  (std layout, RoPE'd)
    u16* vbuf = (u16*)(ws + 83886080);     // 16 MB  (PERMUTED layout, RoPE'd)
    float* ct = (float*)(ws + 100663296);  // 256 KB
    float* st = (float*)(ws + 100925440);  // 256 KB
    float* lrb = (float*)(ws + 101187584); // 512 KB
    u16* ysb = (u16*)(ws + 101711872);     // 16 MB (bf16, permuted space)
    float* pgp = (float*)(ws + 118489088); // 8 KB
    float* pbp = (float*)(ws + 118497280); // 8 KB
    u16* lnb = (u16*)(ws + 0);             // reuse xbf region (dead after QKV GEMMs + k_lr)

    k_cvt5<<<dim3(4096, 6), 256, 0, stream>>>(x, Wq, Wk, Wv, Wo, xbf, wqb, wkb, wvb, wob);
    k_trig<<<256, 256, 0, stream>>>(pf, ct, st);
    k_ppg<<<8, 256, 0, stream>>>(pg, pb, pgp, pbp);

    k_gemm_bt<1><<<dim3(16, 32, 3), 256, 0, stream>>>(xbf, wqb, wkb, wvb, qbuf, kbuf, vbuf,
                                                      4096, 2048, 2048, ct, st);

    k_lr<<<1024, 256, 0, stream>>>(xbf, ilrW, ilrb, lrb);

    k_scan<<<64, 64, 0, stream>>>(qbuf, kbuf, vbuf, lrb, lgs, tg, tb, W0, b0, ysb);

    k_postln<<<4096, 256, 0, stream>>>(ysb, pgp, pbp, lnb);
    k_gemm_bt<0><<<dim3(16, 32, 1), 256, 0, stream>>>(lnb, wob, wob, wob, out, out, out,
                                                      4096, 2048, 2048, nullptr, nullptr);
}

// Round 5
// 740.583 us; speedup vs baseline: 1.6407x; 1.0783x over previous
//
#include <hip/hip_runtime.h>
#include <hip/hip_bf16.h>
#include <math.h>

// Problem constants
#define BB 2
#define SS 2048
#define DD 2048
#define HH 32
#define HDD 64
#define MBB 16
#define NN 128

typedef unsigned short u16;
typedef short bf16x8_t __attribute__((ext_vector_type(8)));
typedef float f32x4_t __attribute__((ext_vector_type(4)));

__device__ __forceinline__ float b2f(u16 u) { return __uint_as_float(((unsigned)u) << 16); }
__device__ __forceinline__ u16 f2b(float f) {
    unsigned u = __float_as_uint(f);
    return (u16)((u + 0x7FFFu + ((u >> 16) & 1u)) >> 16);
}
__device__ __forceinline__ unsigned pk2(float a, float b) {
    return (unsigned)f2b(a) | ((unsigned)f2b(b) << 16);
}
// HW packed f32->bf16 (RNE, same rounding as f2b) — 1 instr instead of ~10
__device__ __forceinline__ unsigned cvtpk(float lo, float hi) {
    unsigned r;
    asm("v_cvt_pk_bf16_f32 %0, %1, %2" : "=v"(r) : "v"(lo), "v"(hi));
    return r;
}
__device__ __forceinline__ unsigned pk2r(u16 a, u16 b) { return (unsigned)a | ((unsigned)b << 16); }
__device__ __forceinline__ float wsum(float x) {
    x += __shfl_xor(x, 32);
    x += __shfl_xor(x, 16);
    x += __shfl_xor(x, 8);
    x += __shfl_xor(x, 4);
    x += __shfl_xor(x, 2);
    x += __shfl_xor(x, 1);
    return x;
}

// DPP-based 16-lane row reduction: pure VALU (no LDS unit), ~4 dependent adds.
// Tree: xor1 (quad_perm), xor2 (quad_perm), then half_mirror / mirror merge the
// (already equal) quads -> bit-identical to the xor1/2/4/8 pairwise tree.
template <int CTRL>
__device__ __forceinline__ float dppadd(float x) {
    int t = __builtin_amdgcn_update_dpp(0, __float_as_int(x), CTRL, 0xF, 0xF, true);
    return x + __int_as_float(t);
}
__device__ __forceinline__ float rsum16(float x) {
    x = dppadd<0xB1>(x);   // quad_perm [1,0,3,2]  = xor1
    x = dppadd<0x4E>(x);   // quad_perm [2,3,0,1]  = xor2
    x = dppadd<0x141>(x);  // row_half_mirror      (merges quad pairs)
    x = dppadd<0x140>(x);  // row_mirror           (merges row halves)
    return x;
}

typedef __attribute__((address_space(3))) unsigned int lds_u32;
typedef __attribute__((address_space(1))) const unsigned int glb_u32;
__device__ __forceinline__ void async_copy16(const void* g, void* l) {
    __builtin_amdgcn_global_load_lds((glb_u32*)g, (lds_u32*)l, 16, 0, 0);
}

// within-head permutation: perm(d) = (d&15)*4 + (d>>4);  inverse: d = (j>>2) + (j&3)*16

// ---------------- fused fp32 -> bf16 for x + 4 weight matrices ----------------
// grid (4096, 6): slice 0,1 = x halves; 2..5 = Wq,Wk,Wv,Wo. 4194304 elems/slice.
// Wo (slice 5) stored with permuted k-columns to match permuted lnb (joint k-perm is GEMM-invariant).
__global__ __launch_bounds__(256) void k_cvt5(const float* __restrict__ x, const float* __restrict__ wq,
                                              const float* __restrict__ wk, const float* __restrict__ wv,
                                              const float* __restrict__ wo, u16* __restrict__ xb,
                                              u16* __restrict__ wqb, u16* __restrict__ wkb,
                                              u16* __restrict__ wvb, u16* __restrict__ wob) {
    int sl = blockIdx.y;
    long e = (long)(blockIdx.x * 256 + threadIdx.x) * 4;
    if (sl == 5) {
        long n = e >> 11;
        int cin = (int)(e & 2047);
        int hd0 = (cin >> 6) * 64 + ((cin & 63) >> 2);
        const float* src = wo + n * 2048 + hd0;
        float f0 = src[0], f1 = src[16], f2 = src[32], f3 = src[48];
        uint2 o;
        o.x = pk2(f0, f1);
        o.y = pk2(f2, f3);
        *(uint2*)(wob + e) = o;
        return;
    }
    const float* s;
    u16* d;
    if (sl == 0) { s = x; d = xb; }
    else if (sl == 1) { s = x + 4194304; d = xb + 4194304; }
    else if (sl == 2) { s = wq; d = wqb; }
    else if (sl == 3) { s = wk; d = wkb; }
    else { s = wv; d = wvb; }
    float4 f = *(const float4*)(s + e);
    uint2 o;
    o.x = pk2(f.x, f.y);
    o.y = pk2(f.z, f.w);
    *(uint2*)(d + e) = o;
}

// ---------------- cos/sin tables ----------------
__global__ void k_trig(const float* __restrict__ pf, float* __restrict__ ct, float* __restrict__ st) {
    int i = blockIdx.x * 256 + threadIdx.x;  // 65536 = S*32
    float f = pf[i];
    ct[i] = cosf(f);
    st[i] = sinf(f);
}

// ---------------- permuted post-LN gamma/beta ----------------
__global__ void k_ppg(const float* __restrict__ pg, const float* __restrict__ pb,
                      float* __restrict__ pgp, float* __restrict__ pbp) {
    int i = blockIdx.x * 256 + threadIdx.x;  // 2048
    int h = i >> 6, o = i & 63;
    int src = h * 64 + (o >> 2) + (o & 3) * 16;
    pgp[i] = pg[src];
    pbp[i] = pb[src];
}

// ---------------- bf16 MFMA GEMM:  C[M,N] = A[M,K] * B[N,K]^T ----------------
// EPI 0: store fp32 row-major; EPI 1: RoPE, bf16 (B,H,S,HD); z==2 (V) stores within-head permuted
template <int EPI>
__global__ __launch_bounds__(256) void k_gemm_bt(const u16* __restrict__ A, const u16* __restrict__ B0,
                                                 const u16* __restrict__ B1, const u16* __restrict__ B2,
                                                 void* __restrict__ C0, void* __restrict__ C1,
                                                 void* __restrict__ C2, int M, int Nn, int K,
                                                 const float* __restrict__ ct, const float* __restrict__ st) {
    __shared__ u16 As[128 * 32];
    __shared__ u16 Bs[128 * 32];
    int z = blockIdx.z;
    const u16* Bm = (z == 0) ? B0 : (z == 1) ? B1 : B2;
    void* Cout = (z == 0) ? C0 : (z == 1) ? C1 : C2;
    int tid = threadIdx.x, lane = tid & 63, wv = tid >> 6;
    int m0 = blockIdx.y * 128, n0 = blockIdx.x * 128;
    int wm = wv >> 1, wn = wv & 1;

    f32x4_t acc[4][4];
    f32x4_t zero = {0.f, 0.f, 0.f, 0.f};
#pragma unroll
    for (int a = 0; a < 4; ++a)
#pragma unroll
        for (int b = 0; b < 4; ++b) acc[a][b] = zero;

    int mrow = lane & 15, qk = (lane >> 4) * 8;
    const int kTiles = K >> 5;
    for (int kt = 0; kt < kTiles; ++kt) {
        __syncthreads();
        int kb = kt << 5;
#pragma unroll
        for (int it = 0; it < 2; ++it) {
            int cb = it * 256 + wv * 64;  // wave-uniform chunk base
            int c = cb + lane;
            const u16* gpA = A + (m0 + (c >> 2)) * K + kb + ((c & 3) << 3);
            async_copy16(gpA, &As[cb << 3]);
            const u16* gpB = Bm + (n0 + (c >> 2)) * K + kb + ((c & 3) << 3);
            async_copy16(gpB, &Bs[cb << 3]);
        }
        asm volatile("s_waitcnt vmcnt(0)" ::: "memory");
        __syncthreads();

        bf16x8_t af[4], bfr[4];
#pragma unroll
        for (int mi = 0; mi < 4; ++mi)
            af[mi] = *(const bf16x8_t*)&As[(wm * 64 + mi * 16 + mrow) * 32 + qk];
#pragma unroll
        for (int ni = 0; ni < 4; ++ni)
            bfr[ni] = *(const bf16x8_t*)&Bs[(wn * 64 + ni * 16 + mrow) * 32 + qk];
#pragma unroll
        for (int mi = 0; mi < 4; ++mi)
#pragma unroll
            for (int ni = 0; ni < 4; ++ni)
                acc[mi][ni] = __builtin_amdgcn_mfma_f32_16x16x32_bf16(af[mi], bfr[ni], acc[mi][ni], 0, 0, 0);
    }

    int col16 = lane & 15, rq = (lane >> 4) * 4;
#pragma unroll
    for (int mi = 0; mi < 4; ++mi) {
#pragma unroll
        for (int ni = 0; ni < 4; ++ni) {
#pragma unroll
            for (int r = 0; r < 4; ++r) {
                int gr = m0 + wm * 64 + mi * 16 + rq + r;
                int gc = n0 + wn * 64 + ni * 16 + col16;
                float val = acc[mi][ni][r];
                if (EPI == 0) {
                    ((float*)Cout)[gr * Nn + gc] = val;
                } else {
                    // fused RoPE: pair partner sits on lane^1 (gc differs in bit 0)
                    int b = gr >> 11, s2 = gr & 2047, hh = gc >> 6, hd = gc & 63;
                    int fi = s2 * 32 + (hd >> 1);
                    float c = ct[fi], sn = st[fi];
                    float partner = __shfl_xor(val, 1);
                    float y = (gc & 1) ? (partner * sn + val * c) : (val * c - partner * sn);
                    int po = (z == 2) ? ((hd & 15) * 4 + (hd >> 4)) : hd;  // V stored permuted
                    ((u16*)Cout)[(((b * HH + hh) * SS) + s2) * HDD + po] = f2b(y);
                }
            }
        }
    }
}

// ---------------- ilr gate ----------------
__global__ __launch_bounds__(256) void k_lr(const u16* __restrict__ xb, const float* __restrict__ ilrW,
                                            const float* __restrict__ ilrb, float* __restrict__ lrout) {
    __shared__ u16 xr[4][2048];
    int row0 = blockIdx.x * 4;
    int tid = threadIdx.x, lane = tid & 63, wv = tid >> 6;
    const unsigned* src = (const unsigned*)(xb + row0 * 2048);
    unsigned* dst = (unsigned*)xr;
    for (int i = tid; i < 4096; i += 256) dst[i] = src[i];
    __syncthreads();
    int b = row0 >> 11, s0 = row0 & 2047;
#pragma unroll
    for (int sub = 0; sub < 8; ++sub) {
        int h = wv * 8 + sub;
        const float* wp = ilrW + h * 2048;
        float a0 = 0.f, a1 = 0.f, a2 = 0.f, a3 = 0.f;
        for (int i = 0; i < 16; ++i) {
            int idx = i * 128 + lane * 2;
            float2 w2 = *(const float2*)(wp + idx);
            unsigned p0 = *(const unsigned*)&xr[0][idx];
            unsigned p1 = *(const unsigned*)&xr[1][idx];
            unsigned p2 = *(const unsigned*)&xr[2][idx];
            unsigned p3 = *(const unsigned*)&xr[3][idx];
            a0 += b2f((u16)p0) * w2.x + b2f((u16)(p0 >> 16)) * w2.y;
            a1 += b2f((u16)p1) * w2.x + b2f((u16)(p1 >> 16)) * w2.y;
            a2 += b2f((u16)p2) * w2.x + b2f((u16)(p2 >> 16)) * w2.y;
            a3 += b2f((u16)p3) * w2.x + b2f((u16)(p3 >> 16)) * w2.y;
        }
        a0 = wsum(a0);
        a1 = wsum(a1);
        a2 = wsum(a2);
        a3 = wsum(a3);
        if (lane == 0) {
            float bv = ilrb[h];
            float* op = lrout + ((b * HH + h) * SS) + s0;
            op[0] = (1.0f / (1.0f + expf(-(a0 + bv)))) * (1.0f / 64.0f);
            op[1] = (1.0f / (1.0f + expf(-(a1 + bv)))) * (1.0f / 64.0f);
            op[2] = (1.0f / (1.0f + expf(-(a2 + bv)))) * (1.0f / 64.0f);
            op[3] = (1.0f / (1.0f + expf(-(a3 + bv)))) * (1.0f / 64.0f);
        }
    }
}

// ---------------- TTT scan: ONE WAVE per (b,h) ----------------
// Latency-bound (wall time = 128 * per-step critical path). Round-5 change:
// all 16-lane reductions now run on the VALU via DPP (rsum16) instead of
// ds_bpermute-based __shfl_xor — removes ~128 LDS-unit ops/step from the chain.
__global__ __launch_bounds__(64, 1) void k_scan(const u16* __restrict__ qb, const u16* __restrict__ kb2,
                                                const u16* __restrict__ vc, const float* __restrict__ lrbuf,
                                                const float* __restrict__ lgs, const float* __restrict__ tg,
                                                const float* __restrict__ tb, const float* __restrict__ W0,
                                                const float* __restrict__ b0, u16* __restrict__ ys) {
    __shared__ u16 WbL[64 * 72];  // [d2][d1]
    __shared__ u16 XKT[64 * 40];  // [d1][j(32)]  j>=16 stays 0
    __shared__ u16 GST[64 * 40];  // [d2][j(32)]  j>=16 stays 0
    __shared__ u16 PUL[16 * 40];  // [i][j(32)]   j>=16 stays 0 (bf16)

    const int bh = blockIdx.x, h = bh & 31, b = bh >> 5;
    const int lane = threadIdx.x & 63;
    const int quad = lane >> 4, col = lane & 15;
    const int base = bh * SS;

    {  // zero-init (upper j-halves must stay zero forever)
        unsigned* p1 = (unsigned*)XKT;
        unsigned* p2 = (unsigned*)GST;
        unsigned* p3 = (unsigned*)PUL;
        for (int i = lane; i < 1280; i += 64) { p1[i] = 0; p2[i] = 0; }
        for (int i = lane; i < 320; i += 64) p3[i] = 0;
    }

    float gd4[4], bd4[4], bbv[4], g2[4], gb[4];
#pragma unroll
    for (int tn = 0; tn < 4; ++tn) {
        gd4[tn] = tg[h * 64 + tn * 16 + col];
        bd4[tn] = tb[h * 64 + tn * 16 + col];
        bbv[tn] = b0[h * 64 + tn * 16 + col];
        g2[tn] = gd4[tn] * gd4[tn];
        gb[tn] = gd4[tn] * bd4[tn];
    }
    float G2m;  // mean over d of gamma^2 (per-head constant)
    {
        float s = g2[0] + g2[1] + g2[2] + g2[3];
        s = rsum16(s);
        G2m = s * (1.f / 64.f);
    }
    float gs4[4];
#pragma unroll
    for (int r = 0; r < 4; ++r) {
        int i = quad * 4 + r;
        gs4[r] = fmaxf(1.f / (float)(i + 1) + lgs[i], 0.f);
    }
    const float gs15 = fmaxf(1.f / 16.f + lgs[15], 0.f);

    f32x4_t Wc[4][4];
#pragma unroll
    for (int tm = 0; tm < 4; ++tm)
#pragma unroll
        for (int tn = 0; tn < 4; ++tn)
#pragma unroll
            for (int r = 0; r < 4; ++r)
                Wc[tm][tn][r] = W0[h * 4096 + (tm * 16 + quad * 4 + r) * 64 + tn * 16 + col];

    {  // initial Wb
        unsigned* wb32 = (unsigned*)WbL;
#pragma unroll
        for (int tn = 0; tn < 4; ++tn)
#pragma unroll
            for (int tm = 0; tm < 4; ++tm) {
                int a = (tn * 16 + col) * 36 + tm * 8 + quad * 2;  // u32 units; row stride 36 u32
                wb32[a] = cvtpk(Wc[tm][tn][0], Wc[tm][tn][1]);
                wb32[a + 1] = cvtpk(Wc[tm][tn][2], Wc[tm][tn][3]);
            }
    }

    // prefetch chunk 0
    bf16x8_t ka[2], qa[2];
    float lr4[4];
    u16 kraw[16], vraw[16], qraw[16];
    {
        const u16* kp = kb2 + (base + col) * 64;
        const u16* qp = qb + (base + col) * 64;
#pragma unroll
        for (int kh = 0; kh < 2; ++kh) {
            ka[kh] = *(const bf16x8_t*)(kp + kh * 32 + quad * 8);
            qa[kh] = *(const bf16x8_t*)(qp + kh * 32 + quad * 8);
        }
#pragma unroll
        for (int r = 0; r < 4; ++r) lr4[r] = lrbuf[base + quad * 4 + r];
#pragma unroll
        for (int tn = 0; tn < 4; ++tn)
#pragma unroll
            for (int r = 0; r < 4; ++r) {
                int idx = (base + quad * 4 + r) * 64 + tn * 16 + col;
                kraw[tn * 4 + r] = kb2[idx];
                qraw[tn * 4 + r] = qb[idx];
            }
#pragma unroll
        for (int r = 0; r < 4; ++r) {
            long ro = (long)(base + quad * 4 + r) * 64 + col * 4;
            ushort4 tv = *(const ushort4*)(vc + ro);
            vraw[r] = tv.x; vraw[4 + r] = tv.y; vraw[8 + r] = tv.z; vraw[12 + r] = tv.w;
        }
    }

    // prologue: XKT(0) write + xkf(0) read; wbf(0) read
    bf16x8_t xkf[4], wbf[4][2];
    {
        unsigned* x32 = (unsigned*)XKT;
#pragma unroll
        for (int tn = 0; tn < 4; ++tn) {
            int a = (tn * 16 + col) * 20 + quad * 2;
            x32[a] = pk2r(kraw[tn * 4 + 0], kraw[tn * 4 + 1]);
            x32[a + 1] = pk2r(kraw[tn * 4 + 2], kraw[tn * 4 + 3]);
        }
#pragma unroll
        for (int t = 0; t < 4; ++t)
            xkf[t] = *(const bf16x8_t*)&XKT[(t * 16 + col) * 40 + quad * 8];
#pragma unroll
        for (int tn = 0; tn < 4; ++tn)
#pragma unroll
            for (int kh = 0; kh < 2; ++kh)
                wbf[tn][kh] = *(const bf16x8_t*)&WbL[(tn * 16 + col) * 72 + kh * 32 + quad * 8];
    }

    const f32x4_t zf = {0.f, 0.f, 0.f, 0.f};

    for (int n = 0; n < NN; ++n) {
        const int s0 = n * 16;

        // Z = XK@W, XQW = XQ@W, Attn = XQ@XK^T  (operands all in regs)
        f32x4_t z[4], xqw[4], attn;
#pragma unroll
        for (int tn = 0; tn < 4; ++tn) {
            z[tn] = __builtin_amdgcn_mfma_f32_16x16x32_bf16(ka[1], wbf[tn][1], zf, 0, 0, 0);
            z[tn] = __builtin_amdgcn_mfma_f32_16x16x32_bf16(ka[0], wbf[tn][0], z[tn], 0, 0, 0);
            xqw[tn] = __builtin_amdgcn_mfma_f32_16x16x32_bf16(qa[1], wbf[tn][1], zf, 0, 0, 0);
            xqw[tn] = __builtin_amdgcn_mfma_f32_16x16x32_bf16(qa[0], wbf[tn][0], xqw[tn], 0, 0, 0);
        }
        attn = __builtin_amdgcn_mfma_f32_16x16x32_bf16(qa[1], ka[1], zf, 0, 0, 0);
        attn = __builtin_amdgcn_mfma_f32_16x16x32_bf16(qa[0], ka[0], attn, 0, 0, 0);

        // Pu = tril(1 + Attn) -> LDS early
#pragma unroll
        for (int r = 0; r < 4; ++r) {
            float pv = (col <= quad * 4 + r) ? (1.f + attn[r]) : 0.f;
            PUL[(quad * 4 + r) * 40 + col] = f2b(pv);
        }

        // prefetch next chunk (clamped on last iter)
        bf16x8_t nka[2], nqa[2];
        float nlr[4];
        u16 nkraw[16], nvraw[16], nqraw[16];
        {
            const int sp = (n + 1 < NN) ? s0 + 16 : s0;
            const u16* kp = kb2 + (base + sp + col) * 64;
            const u16* qp = qb + (base + sp + col) * 64;
#pragma unroll
            for (int kh = 0; kh < 2; ++kh) {
                nka[kh] = *(const bf16x8_t*)(kp + kh * 32 + quad * 8);
                nqa[kh] = *(const bf16x8_t*)(qp + kh * 32 + quad * 8);
            }
#pragma unroll
            for (int r = 0; r < 4; ++r) nlr[r] = lrbuf[base + sp + quad * 4 + r];
#pragma unroll
            for (int tn = 0; tn < 4; ++tn)
#pragma unroll
                for (int r = 0; r < 4; ++r) {
                    int idx = (base + sp + quad * 4 + r) * 64 + tn * 16 + col;
                    nkraw[tn * 4 + r] = kb2[idx];
                    nqraw[tn * 4 + r] = qb[idx];
                }
#pragma unroll
            for (int r = 0; r < 4; ++r) {
                long ro = (long)(base + sp + quad * 4 + r) * 64 + col * 4;
                ushort4 tv = *(const ushort4*)(vc + ro);
                nvraw[r] = tv.x; nvraw[4 + r] = tv.y; nvraw[8 + r] = tv.z; nvraw[12 + r] = tv.w;
            }
        }

        // Z += bb ; fused ln_l2_bwd: single DPP reduce phase over 6 sums
#pragma unroll
        for (int tn = 0; tn < 4; ++tn)
#pragma unroll
            for (int r = 0; r < 4; ++r) z[tn][r] += bbv[tn];

        float c1[16];
        float A1[4], A2[4], A3[4], A4[4], A5[4], A6[4];
#pragma unroll
        for (int r = 0; r < 4; ++r) { A1[r] = 0.f; A2[r] = 0.f; A3[r] = 0.f; A4[r] = 0.f; A5[r] = 0.f; A6[r] = 0.f; }
#pragma unroll
        for (int tn = 0; tn < 4; ++tn)
#pragma unroll
            for (int r = 0; r < 4; ++r) {
                float zv = z[tn][r];
                float tgt = b2f(vraw[tn * 4 + r]) - b2f(kraw[tn * 4 + r]);
                float c = gb[tn] - gd4[tn] * tgt;  // g*(b - tgt)
                c1[tn * 4 + r] = c;
                float t = g2[tn] * zv;
                A1[r] += zv;
                A2[r] = fmaf(zv, zv, A2[r]);
                A3[r] += t;
                A4[r] = fmaf(t, zv, A4[r]);
                A5[r] = fmaf(c, zv, A5[r]);
                A6[r] += c;
            }
#pragma unroll
        for (int r = 0; r < 4; ++r) {
            A1[r] = rsum16(A1[r]);
            A2[r] = rsum16(A2[r]);
            A3[r] = rsum16(A3[r]);
            A4[r] = rsum16(A4[r]);
            A5[r] = rsum16(A5[r]);
            A6[r] = rsum16(A6[r]);
        }
        float mu4[4], rstd4[4], m1[4], m2[4], rl[4];
#pragma unroll
        for (int r = 0; r < 4; ++r) {
            float mu = A1[r] * (1.f / 64.f);
            float var = A2[r] * (1.f / 64.f) - mu * mu;
            float rstd = rsqrtf(var + 1e-5f);
            float T1m = A3[r] * (1.f / 64.f);
            float T2m = A4[r] * (1.f / 64.f);
            float T3m = A5[r] * (1.f / 64.f);
            float C1m = A6[r] * (1.f / 64.f);
            m1[r] = rstd * (T1m - mu * G2m) + C1m;
            m2[r] = rstd * rstd * (T2m - 2.f * mu * T1m + mu * mu * G2m) + rstd * (T3m - mu * C1m);
            mu4[r] = mu;
            rstd4[r] = rstd;
            rl[r] = rstd * lr4[r];
        }
        float gS[4][4];  // lr[j] * grad[j][d]  (C-layout)
#pragma unroll
        for (int tn = 0; tn < 4; ++tn)
#pragma unroll
            for (int r = 0; r < 4; ++r) {
                float zh = (z[tn][r] - mu4[r]) * rstd4[r];
                float dzh = fmaf(g2[tn], zh, c1[tn * 4 + r]);
                gS[tn][r] = fmaf(-m2[r], zh, dzh - m1[r]) * rl[r];
            }
        {  // gradS^T into LDS
            unsigned* g32 = (unsigned*)GST;
#pragma unroll
            for (int tn = 0; tn < 4; ++tn) {
                int a = (tn * 16 + col) * 20 + quad * 2;
                g32[a] = cvtpk(gS[tn][0], gS[tn][1]);
                g32[a + 1] = cvtpk(gS[tn][2], gS[tn][3]);
            }
        }

        // fragment reads
        bf16x8_t gsf[4], puf;
#pragma unroll
        for (int t = 0; t < 4; ++t)
            gsf[t] = *(const bf16x8_t*)&GST[(t * 16 + col) * 40 + quad * 8];
        puf = *(const bf16x8_t*)&PUL[col * 40 + quad * 8];

        // W update first (hoisted wbf read below gets the epilogue to cover latency)
#pragma unroll
        for (int tm = 0; tm < 4; ++tm)
#pragma unroll
            for (int tn = 0; tn < 4; ++tn) {
                f32x4_t dw = __builtin_amdgcn_mfma_f32_16x16x32_bf16(xkf[tm], gsf[tn], zf, 0, 0, 0);
#pragma unroll
                for (int r = 0; r < 4; ++r) Wc[tm][tn][r] -= gs15 * dw[r];
            }
        {
            unsigned* wb32 = (unsigned*)WbL;
#pragma unroll
            for (int tn = 0; tn < 4; ++tn)
#pragma unroll
                for (int tm = 0; tm < 4; ++tm) {
                    int a = (tn * 16 + col) * 36 + tm * 8 + quad * 2;
                    wb32[a] = cvtpk(Wc[tm][tn][0], Wc[tm][tn][1]);
                    wb32[a + 1] = cvtpk(Wc[tm][tn][2], Wc[tm][tn][3]);
                }
        }

        // Z_bar = XQW + bb - gs[i] * (Pu @ gradS)
#pragma unroll
        for (int tn = 0; tn < 4; ++tn) {
            f32x4_t pg = __builtin_amdgcn_mfma_f32_16x16x32_bf16(puf, gsf[tn], zf, 0, 0, 0);
#pragma unroll
            for (int r = 0; r < 4; ++r) z[tn][r] = xqw[tn][r] + bbv[tn] - gs4[r] * pg[r];
        }
        // y = XQ + ln_fwd(Z_bar)  -> bf16 (permuted layout, uint2 store)
#pragma unroll
        for (int r = 0; r < 4; ++r) {
            float s1 = z[0][r] + z[1][r] + z[2][r] + z[3][r];
            float s2 = z[0][r] * z[0][r] + z[1][r] * z[1][r] + z[2][r] * z[2][r] + z[3][r] * z[3][r];
            s1 = rsum16(s1);
            s2 = rsum16(s2);
            float mu = s1 * (1.f / 64.f);
            float var = s2 * (1.f / 64.f) - mu * mu;
            mu4[r] = mu;
            rstd4[r] = rsqrtf(var + 1e-5f);
        }
#pragma unroll
        for (int r = 0; r < 4; ++r) {
            float y0 = b2f(qraw[0 * 4 + r]) + gd4[0] * (z[0][r] - mu4[r]) * rstd4[r] + bd4[0];
            float y1 = b2f(qraw[1 * 4 + r]) + gd4[1] * (z[1][r] - mu4[r]) * rstd4[r] + bd4[1];
            float y2 = b2f(qraw[2 * 4 + r]) + gd4[2] * (z[2][r] - mu4[r]) * rstd4[r] + bd4[2];
            float y3 = b2f(qraw[3 * 4 + r]) + gd4[3] * (z[3][r] - mu4[r]) * rstd4[r] + bd4[3];
            uint2 po;
            po.x = cvtpk(y0, y1);
            po.y = cvtpk(y2, y3);
            *(uint2*)(ys + (long)(b * SS + s0 + quad * 4 + r) * DD + h * 64 + col * 4) = po;
        }

        // b update: bb -= gs15 * colsum(gradS)  (xor16/xor32 cross rows -> keep shfl)
#pragma unroll
        for (int tn = 0; tn < 4; ++tn) {
            float c = gS[tn][0] + gS[tn][1] + gS[tn][2] + gS[tn][3];
            c += __shfl_xor(c, 16);
            c += __shfl_xor(c, 32);
            bbv[tn] -= gs15 * c;
        }

        // hoisted: XKT(n+1) write from prefetched nkraw, then xkf(n+1) + wbf(n+1) reads
        {
            unsigned* x32 = (unsigned*)XKT;
#pragma unroll
            for (int tn = 0; tn < 4; ++tn) {
                int a = (tn * 16 + col) * 20 + quad * 2;
                x32[a] = pk2r(nkraw[tn * 4 + 0], nkraw[tn * 4 + 1]);
                x32[a + 1] = pk2r(nkraw[tn * 4 + 2], nkraw[tn * 4 + 3]);
            }
#pragma unroll
            for (int t = 0; t < 4; ++t)
                xkf[t] = *(const bf16x8_t*)&XKT[(t * 16 + col) * 40 + quad * 8];
#pragma unroll
            for (int tn = 0; tn < 4; ++tn)
#pragma unroll
                for (int kh = 0; kh < 2; ++kh)
                    wbf[tn][kh] = *(const bf16x8_t*)&WbL[(tn * 16 + col) * 72 + kh * 32 + quad * 8];
        }

        ka[0] = nka[0]; ka[1] = nka[1];
        qa[0] = nqa[0]; qa[1] = nqa[1];
#pragma unroll
        for (int r = 0; r < 4; ++r) lr4[r] = nlr[r];
#pragma unroll
        for (int j = 0; j < 16; ++j) { kraw[j] = nkraw[j]; vraw[j] = nvraw[j]; qraw[j] = nqraw[j]; }
    }
}

// ---------------- post layernorm (bf16 in, PERMUTED space) -> bf16 out (permuted) ----------------
__global__ __launch_bounds__(256) void k_postln(const u16* __restrict__ ys, const float* __restrict__ pg,
                                                const float* __restrict__ pb, u16* __restrict__ outb) {
    __shared__ float red[8];
    int row = blockIdx.x, tid = threadIdx.x, lane = tid & 63, wv = tid >> 6;
    const u16* rp = ys + row * 2048 + tid * 8;
    uint4 pkd = *(const uint4*)rp;
    float v[8];
    v[0] = b2f((u16)pkd.x); v[1] = b2f((u16)(pkd.x >> 16));
    v[2] = b2f((u16)pkd.y); v[3] = b2f((u16)(pkd.y >> 16));
    v[4] = b2f((u16)pkd.z); v[5] = b2f((u16)(pkd.z >> 16));
    v[6] = b2f((u16)pkd.w); v[7] = b2f((u16)(pkd.w >> 16));
    float s1 = 0.f, s2 = 0.f;
#pragma unroll
    for (int i = 0; i < 8; ++i) { s1 += v[i]; s2 += v[i] * v[i]; }
    s1 = wsum(s1);
    s2 = wsum(s2);
    if (lane == 0) {
        red[wv] = s1;
        red[wv + 4] = s2;
    }
    __syncthreads();
    float S1 = red[0] + red[1] + red[2] + red[3];
    float S2 = red[4] + red[5] + red[6] + red[7];
    float mu = S1 * (1.f / 2048), var = S2 * (1.f / 2048) - mu * mu;
    float rstd = rsqrtf(var + 1e-5f);
    const float4 g0 = *(const float4*)(pg + tid * 8);
    const float4 g1 = *(const float4*)(pg + tid * 8 + 4);
    const float4 b0v = *(const float4*)(pb + tid * 8);
    const float4 b1v = *(const float4*)(pb + tid * 8 + 4);
    float o[8];
    o[0] = g0.x * (v[0] - mu) * rstd + b0v.x;
    o[1] = g0.y * (v[1] - mu) * rstd + b0v.y;
    o[2] = g0.z * (v[2] - mu) * rstd + b0v.z;
    o[3] = g0.w * (v[3] - mu) * rstd + b0v.w;
    o[4] = g1.x * (v[4] - mu) * rstd + b1v.x;
    o[5] = g1.y * (v[5] - mu) * rstd + b1v.y;
    o[6] = g1.z * (v[6] - mu) * rstd + b1v.z;
    o[7] = g1.w * (v[7] - mu) * rstd + b1v.w;
    uint4 po;
    po.x = pk2(o[0], o[1]);
    po.y = pk2(o[2], o[3]);
    po.z = pk2(o[4], o[5]);
    po.w = pk2(o[6], o[7]);
    *(uint4*)(outb + row * 2048 + tid * 8) = po;
}

extern "C" void kernel_launch(void* const* d_in, const int* in_sizes, int n_in,
                              void* d_out, int out_size, void* d_ws, size_t ws_size,
                              hipStream_t stream) {
    const float* x = (const float*)d_in[0];
    const float* pf = (const float*)d_in[1];
    const float* Wq = (const float*)d_in[2];
    const float* Wk = (const float*)d_in[3];
    const float* Wv = (const float*)d_in[4];
    const float* Wo = (const float*)d_in[5];
    const float* pg = (const float*)d_in[6];
    const float* pb = (const float*)d_in[7];
    const float* ilrW = (const float*)d_in[8];
    const float* ilrb = (const float*)d_in[9];
    const float* lgs = (const float*)d_in[10];
    const float* tg = (const float*)d_in[11];
    const float* tb = (const float*)d_in[12];
    const float* W0 = (const float*)d_in[13];
    const float* b0 = (const float*)d_in[14];
    float* out = (float*)d_out;
    char* ws = (char*)d_ws;

    // workspace layout
    u16* xbf = (u16*)(ws + 0);             // 16 MB  (reused as lnb later)
    u16* wqb = (u16*)(ws + 16777216);      // 8 MB
    u16* wkb = (u16*)(ws + 25165824);      // 8 MB
    u16* wvb = (u16*)(ws + 33554432);      // 8 MB
    u16* wob = (u16*)(ws + 41943040);      // 8 MB   (permuted k-columns)
    u16* qbuf = (u16*)(ws + 50331648);     // 16 MB  (std layout, RoPE'd)
    u16* kbuf = (u16*)(ws + 67108864);     // 16 MB  (std layout, RoPE'd)
    u16* vbuf = (u16*)(ws + 83886080);     // 16 MB  (PERMUTED layout, RoPE'd)
    float* ct = (float*)(ws + 100663296);  // 256 KB
    float* st = (float*)(ws + 100925440);  // 256 KB
    float* lrb = (float*)(ws + 101187584); // 512 KB
    u16* ysb = (u16*)(ws + 101711872);     // 16 MB (bf16, permuted space)
    float* pgp = (float*)(ws + 118489088); // 8 KB
    float* pbp = (float*)(ws + 118497280); // 8 KB
    u16* lnb = (u16*)(ws + 0);             // reuse xbf region (dead after QKV GEMMs + k_lr)

    k_cvt5<<<dim3(4096, 6), 256, 0, stream>>>(x, Wq, Wk, Wv, Wo, xbf, wqb, wkb, wvb, wob);
    k_trig<<<256, 256, 0, stream>>>(pf, ct, st);
    k_ppg<<<8, 256, 0, stream>>>(pg, pb, pgp, pbp);

    k_gemm_bt<1><<<dim3(16, 32, 3), 256, 0, stream>>>(xbf, wqb, wkb, wvb, qbuf, kbuf, vbuf,
                                                      4096, 2048, 2048, ct, st);

    k_lr<<<1024, 256, 0, stream>>>(xbf, ilrW, ilrb, lrb);

    k_scan<<<64, 64, 0, stream>>>(qbuf, kbuf, vbuf, lrb, lgs, tg, tb, W0, b0, ysb);

    k_postln<<<4096, 256, 0, stream>>>(ysb, pgp, pbp, lnb);
    k_gemm_bt<0><<<dim3(16, 32, 1), 256, 0, stream>>>(lnb, wob, wob, wob, out, out, out,
                                                      4096, 2048, 2048, nullptr, nullptr);
}